// Round 13
// baseline (505.673 us; speedup 1.0000x reference)
//
#include <hip/hip_runtime.h>
#include <cstddef>

#define NEG_SLOPE 0.2f

typedef __attribute__((ext_vector_type(8))) short bf16x8;
typedef __attribute__((ext_vector_type(4))) float f32x4;

__device__ __forceinline__ float leaky(float v) { return v >= 0.f ? v : NEG_SLOPE * v; }

__device__ __forceinline__ unsigned int bfpack(float a, float b) {
    unsigned int ua = __float_as_uint(a);
    ua += 0x7fffu + ((ua >> 16) & 1u);
    unsigned int ub = __float_as_uint(b);
    ub += 0x7fffu + ((ub >> 16) & 1u);
    return (ua >> 16) | (ub & 0xffff0000u);
}
__device__ __forceinline__ float bflo(unsigned int u) { return __uint_as_float(u << 16); }
__device__ __forceinline__ float bfhi(unsigned int u) { return __uint_as_float(u & 0xffff0000u); }
__device__ __forceinline__ float bfs(unsigned short u) { return __uint_as_float(((unsigned int)u) << 16); }

#define NCB 192   // coarse count/scatter blocks

// ================= K1: small-constants (b==0) | weight transpose (b in [1,64]) | coarse count (b>=65) =================
__global__ __launch_bounds__(512) void k_init(const float* __restrict__ rel_emb, const float* __restrict__ W_relT,
                                              const float* __restrict__ W_relprop, const float* __restrict__ b_relprop,
                                              const float* __restrict__ W_fuse, const float* __restrict__ W_src,
                                              const float* __restrict__ b_src, const float* __restrict__ W_node,
                                              const float* __restrict__ b_node, const float* __restrict__ W_g,
                                              const int* __restrict__ src, const int* __restrict__ dst,
                                              int E, int RE,
                                              float* __restrict__ relfeat, float* __restrict__ wes,
                                              float* __restrict__ wed, float* __restrict__ ces, float* __restrict__ ced,
                                              unsigned int* __restrict__ wt, int* __restrict__ bucketTot) {
    __shared__ float av[512];
    __shared__ float rp[2][128];
    __shared__ int h0[256], h1[256], h2[256];
    int b = blockIdx.x;
    int t = threadIdx.x;
    if (b == 0) {
        {
            int r = t >> 8, m = t & 255;
            float acc = 0.f;
            const float* re = rel_emb + r * 64;
            const float* w = W_relT + (size_t)r * 16384 + m;
            #pragma unroll 8
            for (int k = 0; k < 64; ++k) acc += re[k] * w[(size_t)k * 256];
            av[t] = acc;
        }
        if (t < 256) {
            int r = t >> 7, m = t & 127;
            float acc = b_relprop[t];
            const float* re = rel_emb + r * 64;
            const float* w = W_relprop + (size_t)r * 8192 + m;
            #pragma unroll 8
            for (int k = 0; k < 64; ++k) acc += re[k] * w[(size_t)k * 128];
            rp[r][m] = acc;
        }
        __syncthreads();
        if (t < 256) {
            int r = t >> 7, h = (t >> 5) & 3, d = t & 31;
            float acc = 0.f;
            const float* w = W_fuse + ((size_t)(r * 4 + h) * 32) * 32 + d;
            #pragma unroll
            for (int k = 0; k < 32; ++k) acc += rp[r][h * 32 + k] * w[(size_t)k * 32];
            relfeat[t] = acc;
        }
        for (int idx = t; idx < 2048; idx += 512) {
            int which = idx >> 10, rem = idx & 1023;
            int r = rem >> 9, h = (rem >> 7) & 3, c = rem & 127;
            const float* W = which ? W_node : (W_src + (size_t)r * 16384);
            const float* a = av + r * 256 + h * 64 + which * 32;
            float acc = 0.f;
            #pragma unroll
            for (int d = 0; d < 32; ++d) acc += W[(size_t)c * 128 + h * 32 + d] * a[d];
            (which ? wed : wes)[rem] = acc;
        }
        if (t < 16) {
            int which = t >> 3, r = (t >> 2) & 1, h = t & 3;
            const float* bb = which ? b_node : (b_src + r * 128);
            const float* a = av + r * 256 + h * 64 + which * 32;
            float acc = 0.f;
            #pragma unroll
            for (int d = 0; d < 32; ++d) acc += bb[h * 32 + d] * a[d];
            (which ? ced : ces)[r * 4 + h] = acc;
        }
    } else if (b <= 64) {
        int idx = (b - 1) * 512 + t;   // 4*128*64 = 32768
        int mat = idx >> 13, rem = idx & 8191;
        int nrow = rem >> 6, kp = rem & 63;
        const float* W = mat < 2 ? W_src + (size_t)mat * 16384 : (mat == 2 ? W_node : W_g);
        wt[idx] = bfpack(W[(size_t)(2 * kp) * 128 + nrow], W[(size_t)(2 * kp + 1) * 128 + nrow]);
    } else {
        if (t < 256) { h0[t] = 0; h1[t] = 0; h2[t] = 0; }
        __syncthreads();
        int cb = b - 65;
        int chunk = (RE + NCB - 1) / NCB;
        int lo = cb * chunk, hi = min(lo + chunk, RE);
        for (int i = lo + t; i < hi; i += 512) {
            int d = dst[i], s = src[i];
            atomicAdd((i < E ? h0 : h1) + (d >> 9), 1);
            atomicAdd(&h2[s >> 9], 1);
        }
        __syncthreads();
        if (t < 256) {
            if (h0[t]) atomicAdd(&bucketTot[t], h0[t]);
            if (h1[t]) atomicAdd(&bucketTot[256 + t], h1[t]);
            if (h2[t]) atomicAdd(&bucketTot[512 + t], h2[t]);
        }
    }
}

// ================= K2: bucket-scan (b==0) | prep scores + xbp = bf16(x) (b>=1) =================
__global__ __launch_bounds__(256) void k_prepb(const int* __restrict__ bucketTot,
                                               int* __restrict__ bucketBase, int* __restrict__ cursor,
                                               int* __restrict__ ip0, int* __restrict__ ip1, int E,
                                               const float* __restrict__ x,
                                               const float* __restrict__ wes, const float* __restrict__ wed,
                                               const float* __restrict__ ces, const float* __restrict__ ced,
                                               float* __restrict__ es0, float* __restrict__ es1,
                                               float* __restrict__ ed0, float* __restrict__ ed1,
                                               unsigned int* __restrict__ xbp, int n) {
    __shared__ float xs[64 * 132];
    int tid = threadIdx.x;
    if (blockIdx.x == 0) {
        __shared__ int sc[256];
        int t = tid;
        for (int j = 0; j < 3; ++j) {
            int v = bucketTot[j * 256 + t];
            sc[t] = v;
            __syncthreads();
            for (int off = 1; off < 256; off <<= 1) {
                int tmp = (t >= off) ? sc[t - off] : 0;
                __syncthreads();
                sc[t] += tmp;
                __syncthreads();
            }
            int excl = sc[t] - v;
            bucketBase[j * 257 + t] = excl;
            if (t == 255) bucketBase[j * 257 + 256] = sc[255];
            cursor[j * 256 + t] = excl;
            __syncthreads();
        }
        if (t == 0) { ip0[n] = E; ip1[n] = E; }
        return;
    }
    int nb0 = (blockIdx.x - 1) * 64;
    for (int i = tid; i < 64 * 32; i += 256) {
        int row = i >> 5, c4 = i & 31;
        float4 v = make_float4(0.f, 0.f, 0.f, 0.f);
        if (nb0 + row < n) v = *(const float4*)(x + (size_t)(nb0 + row) * 128 + c4 * 4);
        *(float4*)(xs + row * 132 + c4 * 4) = v;
    }
    __syncthreads();
    for (int i = tid; i < 64 * 64; i += 256) {
        int row = i >> 6, c2 = i & 63;
        int gr = nb0 + row;
        if (gr < n)
            xbp[(size_t)gr * 64 + c2] = bfpack(xs[row * 132 + 2 * c2], xs[row * 132 + 2 * c2 + 1]);
    }
    int node = tid >> 2;
    int gn = nb0 + node;
    if (gn >= n) return;
    #pragma unroll
    for (int q = 0; q < 4; ++q) {
        int j = (tid & 3) + q * 4;          // j = which*8 + r*4 + h
        int which = j >> 3, r = (j >> 2) & 1, h = j & 3;
        const float* w = (which ? wed : wes) + r * 512 + h * 128;
        float acc = (which ? ced : ces)[r * 4 + h];
        #pragma unroll 16
        for (int d = 0; d < 128; ++d) acc += xs[node * 132 + d] * w[d];
        float* outp = which ? (r ? ed1 : ed0) : (r ? es1 : es0);
        outp[(size_t)gn * 4 + h] = acc;
    }
}

// ================= K3: coarse scatter (b<NCB, packed) | dual-relation MFMA GEMM (b>=NCB) =================
__global__ __launch_bounds__(256) void k_scmm(const int* __restrict__ src, const int* __restrict__ dst,
                                              int E, int RE, int* __restrict__ cursor,
                                              unsigned int* __restrict__ pairs0, unsigned int* __restrict__ pairs1,
                                              unsigned short* __restrict__ svals,
                                              const unsigned int* __restrict__ xbp,
                                              unsigned int* __restrict__ gx,
                                              const unsigned short* __restrict__ wts,
                                              const float* __restrict__ b_src, int MB, int n) {
    if (blockIdx.x < NCB) {
        __shared__ int h0[256], h1[256], h2[256];
        __shared__ int c0[256], c1[256], c2[256];
        int t = threadIdx.x;
        h0[t] = 0; h1[t] = 0; h2[t] = 0;
        __syncthreads();
        int chunk = (RE + NCB - 1) / NCB;
        int lo = blockIdx.x * chunk, hi = min(lo + chunk, RE);
        for (int i = lo + t; i < hi; i += 256) {
            int d = dst[i], s = src[i];
            atomicAdd((i < E ? h0 : h1) + (d >> 9), 1);
            atomicAdd(&h2[s >> 9], 1);
        }
        __syncthreads();
        if (h0[t]) c0[t] = atomicAdd(&cursor[t], h0[t]);
        if (h1[t]) c1[t] = atomicAdd(&cursor[256 + t], h1[t]);
        if (h2[t]) c2[t] = atomicAdd(&cursor[512 + t], h2[t]);
        __syncthreads();
        for (int i = lo + t; i < hi; i += 256) {
            int d = dst[i], s = src[i];
            unsigned int packed = ((unsigned)(d & 511) << 23) | (unsigned)s;
            if (i < E) {
                int pos = atomicAdd(&c0[d >> 9], 1);
                pairs0[pos] = packed;
            } else {
                int pos = atomicAdd(&c1[d >> 9], 1);
                pairs1[pos] = packed;
            }
            int pos2 = atomicAdd(&c2[s >> 9], 1);
            svals[pos2] = (unsigned short)(s & 511);
        }
        return;
    }
    int q = blockIdx.x - NCB;
    int rel = q / MB, mb = q % MB;
    const unsigned short* wT = wts + (size_t)rel * 16384;
    const float* bias = b_src + rel * 128;
    int wid = threadIdx.x >> 6, lane = threadIdx.x & 63;
    int l15 = lane & 15, g = lane >> 4;
    int m0 = mb * 128 + wid * 32;
    const unsigned short* Au = (const unsigned short*)xbp;
    f32x4 acc[2][8];
    #pragma unroll
    for (int mt = 0; mt < 2; ++mt)
        #pragma unroll
        for (int nt = 0; nt < 8; ++nt)
            #pragma unroll
            for (int r = 0; r < 4; ++r) acc[mt][nt][r] = 0.f;
    #pragma unroll
    for (int t = 0; t < 4; ++t) {
        bf16x8 a0 = *(const bf16x8*)(Au + (size_t)(m0 + l15) * 128 + t * 32 + g * 8);
        bf16x8 a1 = *(const bf16x8*)(Au + (size_t)(m0 + 16 + l15) * 128 + t * 32 + g * 8);
        #pragma unroll
        for (int nt = 0; nt < 8; ++nt) {
            bf16x8 b = *(const bf16x8*)(wT + (size_t)(nt * 16 + l15) * 128 + t * 32 + g * 8);
            acc[0][nt] = __builtin_amdgcn_mfma_f32_16x16x32_bf16(a0, b, acc[0][nt], 0, 0, 0);
            acc[1][nt] = __builtin_amdgcn_mfma_f32_16x16x32_bf16(a1, b, acc[1][nt], 0, 0, 0);
        }
    }
    #pragma unroll
    for (int mt = 0; mt < 2; ++mt)
        #pragma unroll
        for (int nt = 0; nt < 8; ++nt) {
            int col = nt * 16 + l15;
            float bv = bias[col];
            #pragma unroll
            for (int r = 0; r < 4; ++r) {
                int row = m0 + mt * 16 + g * 4 + r;
                float v = acc[mt][nt][r] + bv;
                float vp = __shfl_xor(v, 1);
                if (!(l15 & 1) && row < n)
                    gx[(size_t)row * 192 + rel * 64 + (col >> 1)] = bfpack(v, vp);
            }
        }
}

// ---------- stage 4 (3 jobs): per-bucket fine sort (r=0,1) + out-degree + xn = rsdo*xb (r=2) ----------
__global__ __launch_bounds__(512) void k_fine(const unsigned int* __restrict__ pairs0,
                                              const unsigned int* __restrict__ pairs1,
                                              const unsigned short* __restrict__ svals,
                                              const int* __restrict__ bucketBase,
                                              int* __restrict__ ip0, int* __restrict__ ip1,
                                              int* __restrict__ srcs0, int* __restrict__ srcs1,
                                              const unsigned int* __restrict__ xbp,
                                              unsigned int* __restrict__ gx, int N) {
    int r = blockIdx.y;
    int b = blockIdx.x;
    __shared__ int hist[512];
    int t = threadIdx.x;
    hist[t] = 0;
    __syncthreads();
    if (r == 2) {   // src out-degree histogram -> xn section of gx
        int ebase = bucketBase[2 * 257 + b], eend = bucketBase[2 * 257 + b + 1];
        for (int k = ebase + t; k < eend; k += 512)
            atomicAdd(&hist[svals[k]], 1);
        __syncthreads();
        int wave = t >> 6, lane = t & 63;
        for (int i = 0; i < 64; ++i) {
            int nl = wave * 64 + i;
            int gn = (b << 9) + nl;
            if (gn < N) {
                float rs = rsqrtf(fmaxf((float)hist[nl], 1.f));
                unsigned int u = xbp[(size_t)gn * 64 + lane];
                gx[(size_t)gn * 192 + 128 + lane] = bfpack(bflo(u) * rs, bfhi(u) * rs);
            }
        }
        return;
    }
    const unsigned int* pairs = r ? pairs1 : pairs0;
    int* ip = r ? ip1 : ip0;
    int* srcs = r ? srcs1 : srcs0;
    int ebase = bucketBase[r * 257 + b], eend = bucketBase[r * 257 + b + 1];
    for (int k = ebase + t; k < eend; k += 512)
        atomicAdd(&hist[pairs[k] >> 23], 1);
    __syncthreads();
    int v = hist[t];
    for (int off = 1; off < 512; off <<= 1) {
        int tmp = (t >= off) ? hist[t - off] : 0;
        __syncthreads();
        hist[t] += tmp;
        __syncthreads();
    }
    int excl = hist[t] - v;
    int node = (b << 9) + t;
    if (node < N) ip[node] = ebase + excl;
    __syncthreads();
    hist[t] = ebase + excl;  // reuse as scatter cursor
    __syncthreads();
    for (int k = ebase + t; k < eend; k += 512) {
        unsigned int p = pairs[k];
        int pos = atomicAdd(&hist[p >> 23], 1);
        srcs[pos] = (int)(p & 0x7FFFFFu);
    }
}

// ---------- CSR gather-aggregate: TWO nodes per wave (32 lanes, 4 ch/lane), uint2 gathers ----------
__global__ __launch_bounds__(256) void k_agg(const int* __restrict__ ip0, const int* __restrict__ srcs0,
                                             const int* __restrict__ ip1, const int* __restrict__ srcs1,
                                             const unsigned int* __restrict__ gx,
                                             const float* __restrict__ es0, const float* __restrict__ es1,
                                             const float* __restrict__ ed0, const float* __restrict__ ed1,
                                             const float* __restrict__ relfeat,
                                             unsigned int* __restrict__ fubp, unsigned int* __restrict__ hgbp, int n) {
    int node = blockIdx.x * 8 + (threadIdx.x >> 5);   // one node per 32-lane half-wave
    if (node >= n) return;
    int l = threadIdx.x & 31;                          // channels 4l .. 4l+3
    int h = l >> 3;
    float ed0v = ed0[(size_t)node * 4 + h];
    float ed1v = ed1[(size_t)node * 4 + h];
    float aU0[4] = {0.f, 0.f, 0.f, 0.f};
    float aU1[4] = {0.f, 0.f, 0.f, 0.f};
    float aH[4]  = {0.f, 0.f, 0.f, 0.f};
    float s0 = 0.f, s1 = 0.f;
    int b0 = ip0[node], e0 = ip0[node + 1];
    #pragma unroll 2
    for (int k = b0; k < e0; ++k) {
        int s = srcs0[k];
        float ex = __expf(leaky(es0[(size_t)s * 4 + h] + ed0v));
        size_t base = (size_t)s * 192;
        uint2 fv = *(const uint2*)(gx + base + 2 * l);
        uint2 xv = *(const uint2*)(gx + base + 128 + 2 * l);
        aU0[0] += ex * bflo(fv.x); aU0[1] += ex * bfhi(fv.x);
        aU0[2] += ex * bflo(fv.y); aU0[3] += ex * bfhi(fv.y);
        aH[0] += bflo(xv.x); aH[1] += bfhi(xv.x);
        aH[2] += bflo(xv.y); aH[3] += bfhi(xv.y);
        s0 += ex;
    }
    int b1 = ip1[node], e1 = ip1[node + 1];
    #pragma unroll 2
    for (int k = b1; k < e1; ++k) {
        int s = srcs1[k];
        float ex = __expf(leaky(es1[(size_t)s * 4 + h] + ed1v));
        size_t base = (size_t)s * 192;
        uint2 fv = *(const uint2*)(gx + base + 64 + 2 * l);
        uint2 xv = *(const uint2*)(gx + base + 128 + 2 * l);
        aU1[0] += ex * bflo(fv.x); aU1[1] += ex * bfhi(fv.x);
        aU1[2] += ex * bflo(fv.y); aU1[3] += ex * bfhi(fv.y);
        aH[0] += bflo(xv.x); aH[1] += bfhi(xv.x);
        aH[2] += bflo(xv.y); aH[3] += bfhi(xv.y);
        s1 += ex;
    }
    float i0 = 1.f / (s0 + 1e-9f), i1 = 1.f / (s1 + 1e-9f);
    float f0[4], f1[4];
    #pragma unroll
    for (int c = 0; c < 4; ++c) {
        f0[c] = fmaxf(aU0[c] * i0, 0.f);
        f1[c] = fmaxf(aU1[c] * i1, 0.f);
    }
    float sc0 = 0.f, sc1 = 0.f;
    #pragma unroll
    for (int c = 0; c < 4; ++c) {
        sc0 += f0[c] * relfeat[4 * l + c];
        sc1 += f1[c] * relfeat[128 + 4 * l + c];
    }
    #pragma unroll
    for (int m = 1; m < 8; m <<= 1) {     // reduce over the 8-lane head group
        sc0 += __shfl_xor(sc0, m, 64);
        sc1 += __shfl_xor(sc1, m, 64);
    }
    sc0 = leaky(sc0); sc1 = leaky(sc1);
    float mx = fmaxf(sc0, sc1);
    float p0 = __expf(sc0 - mx), p1 = __expf(sc1 - mx);
    float inv = 1.f / (p0 + p1);
    p0 *= inv; p1 *= inv;
    float rv = rsqrtf(fmaxf((float)((e0 - b0) + (e1 - b1)), 1.f));
    uint2 fo, ho;
    fo.x = bfpack(p0 * f0[0] + p1 * f1[0], p0 * f0[1] + p1 * f1[1]);
    fo.y = bfpack(p0 * f0[2] + p1 * f1[2], p0 * f0[3] + p1 * f1[3]);
    ho.x = bfpack(aH[0] * rv, aH[1] * rv);
    ho.y = bfpack(aH[2] * rv, aH[3] * rv);
    *(uint2*)(fubp + (size_t)node * 64 + 2 * l) = fo;
    *(uint2*)(hgbp + (size_t)node * 64 + 2 * l) = ho;
}

// ---------- final: two MFMA GEMMs (hgb @ Wg, xb @ Wn) + fusion epilogue ----------
__global__ __launch_bounds__(256) void k_fin(const unsigned int* __restrict__ hgbp,
                                             const unsigned int* __restrict__ xbp,
                                             const unsigned short* __restrict__ wtg,
                                             const unsigned short* __restrict__ wtn,
                                             const float* __restrict__ bg, const float* __restrict__ bn,
                                             const unsigned int* __restrict__ fubp,
                                             const float* __restrict__ residual_w, const float* __restrict__ scale_w,
                                             float* __restrict__ out, int n) {
    int wid = threadIdx.x >> 6, lane = threadIdx.x & 63;
    int l15 = lane & 15, g = lane >> 4;
    int m0 = blockIdx.x * 128 + wid * 32;
    const unsigned short* Hu = (const unsigned short*)hgbp;
    const unsigned short* Xu = (const unsigned short*)xbp;
    const unsigned short* Fu = (const unsigned short*)fubp;
    f32x4 accn[2][8], accg[2][8];
    #pragma unroll
    for (int mt = 0; mt < 2; ++mt)
        #pragma unroll
        for (int nt = 0; nt < 8; ++nt)
            #pragma unroll
            for (int r = 0; r < 4; ++r) { accn[mt][nt][r] = 0.f; accg[mt][nt][r] = 0.f; }
    #pragma unroll
    for (int t = 0; t < 4; ++t) {
        bf16x8 a0 = *(const bf16x8*)(Xu + (size_t)(m0 + l15) * 128 + t * 32 + g * 8);
        bf16x8 a1 = *(const bf16x8*)(Xu + (size_t)(m0 + 16 + l15) * 128 + t * 32 + g * 8);
        #pragma unroll
        for (int nt = 0; nt < 8; ++nt) {
            bf16x8 b = *(const bf16x8*)(wtn + (size_t)(nt * 16 + l15) * 128 + t * 32 + g * 8);
            accn[0][nt] = __builtin_amdgcn_mfma_f32_16x16x32_bf16(a0, b, accn[0][nt], 0, 0, 0);
            accn[1][nt] = __builtin_amdgcn_mfma_f32_16x16x32_bf16(a1, b, accn[1][nt], 0, 0, 0);
        }
    }
    #pragma unroll
    for (int t = 0; t < 4; ++t) {
        bf16x8 a0 = *(const bf16x8*)(Hu + (size_t)(m0 + l15) * 128 + t * 32 + g * 8);
        bf16x8 a1 = *(const bf16x8*)(Hu + (size_t)(m0 + 16 + l15) * 128 + t * 32 + g * 8);
        #pragma unroll
        for (int nt = 0; nt < 8; ++nt) {
            bf16x8 b = *(const bf16x8*)(wtg + (size_t)(nt * 16 + l15) * 128 + t * 32 + g * 8);
            accg[0][nt] = __builtin_amdgcn_mfma_f32_16x16x32_bf16(a0, b, accg[0][nt], 0, 0, 0);
            accg[1][nt] = __builtin_amdgcn_mfma_f32_16x16x32_bf16(a1, b, accg[1][nt], 0, 0, 0);
        }
    }
    float beta = 1.f / (1.f + __expf(-residual_w[0]));
    float av = 1.f / (1.f + __expf(-scale_w[0]));
    #pragma unroll
    for (int mt = 0; mt < 2; ++mt)
        #pragma unroll
        for (int nt = 0; nt < 8; ++nt) {
            int col = nt * 16 + l15;
            float bnv = bn[col], bgv = bg[col];
            #pragma unroll
            for (int r = 0; r < 4; ++r) {
                int row = m0 + mt * 16 + g * 4 + r;
                if (row < n) {
                    float fu = bfs(Fu[(size_t)row * 128 + col]);
                    float fd = accn[mt][nt][r] + bnv;
                    float f = beta * fu + (1.f - beta) * fd;
                    float nl = fmaxf(accg[mt][nt][r] + bgv, 0.f);
                    out[(size_t)row * 128 + col] = av * f + (1.f - av) * nl;
                }
            }
        }
}

extern "C" void kernel_launch(void* const* d_in, const int* in_sizes, int n_in,
                              void* d_out, int out_size, void* d_ws, size_t ws_size,
                              hipStream_t stream) {
    const float* x         = (const float*)d_in[0];
    const int*   src       = (const int*)d_in[1];
    const int*   dst       = (const int*)d_in[2];
    const float* rel_emb   = (const float*)d_in[3];
    const float* W_node    = (const float*)d_in[4];
    const float* b_node    = (const float*)d_in[5];
    const float* W_src     = (const float*)d_in[6];
    const float* b_src     = (const float*)d_in[7];
    const float* W_relT    = (const float*)d_in[8];
    const float* W_relprop = (const float*)d_in[9];
    const float* b_relprop = (const float*)d_in[10];
    const float* W_fuse    = (const float*)d_in[11];
    const float* resid_w   = (const float*)d_in[12];
    const float* scale_w   = (const float*)d_in[13];
    const float* W_g       = (const float*)d_in[14];
    const float* b_g       = (const float*)d_in[15];
    float* out = (float*)d_out;

    const int N = in_sizes[0] / 128;
    const int RE = in_sizes[1];
    const int E = RE / 2;
    const int Npad = (N + 127) & ~127;
    const int NBUCK = (N + 511) >> 9;
    const int MB = Npad / 128;

    // workspace (~146 MB at N=1e5, E=1e6)
    float* ws = (float*)d_ws;
    size_t o = 0;
    unsigned int* fubp = (unsigned int*)(ws + o); o += (size_t)Npad * 64;   // fused bf16; aliased by sort scratch early
    unsigned int* gx   = (unsigned int*)(ws + o); o += (size_t)Npad * 192;  // fs0|fs1|xn interleaved (768B rows)
    unsigned int* hgbp = (unsigned int*)(ws + o); o += (size_t)Npad * 64;   // bf16 hg*rsdi
    unsigned int* xbp  = (unsigned int*)(ws + o); o += (size_t)Npad * 64;   // bf16 x (linear, for GEMMs)
    float* es0  = ws + o; o += (size_t)N * 4;
    float* es1  = ws + o; o += (size_t)N * 4;
    float* ed0  = ws + o; o += (size_t)N * 4;
    float* ed1  = ws + o; o += (size_t)N * 4;
    unsigned int* wtu = (unsigned int*)(ws + o); o += 32768;  // bf16 W^T x4 mats
    float* relfeat = ws + o; o += 256;
    float* wes  = ws + o; o += 1024;
    float* wed  = ws + o; o += 1024;
    float* ces  = ws + o; o += 16;
    float* ced  = ws + o; o += 16;
    int* ip0  = (int*)(ws + o); o += N + 1;
    int* ip1  = (int*)(ws + o); o += N + 1;
    int* srcs0 = (int*)(ws + o); o += E;
    int* srcs1 = (int*)(ws + o); o += E;
    int* bucketTot  = (int*)(ws + o); o += 768;
    int* bucketBase = (int*)(ws + o); o += 771;
    int* cursor     = (int*)(ws + o); o += 768;
    // transient sort scratch aliased into fubp region (12 MB <= Npad*256B)
    unsigned int* pairs0 = (unsigned int*)fubp;                 // E uints
    unsigned int* pairs1 = pairs0 + (size_t)E;                  // E uints
    unsigned short* svals = (unsigned short*)(pairs1 + (size_t)E);  // RE ushorts

    const unsigned short* wts = (const unsigned short*)wtu;  // mat m at wts + m*16384

    hipMemsetAsync(bucketTot, 0, 768 * sizeof(int), stream);

    // K1: small | twt | count
    k_init<<<1 + 64 + NCB, 512, 0, stream>>>(rel_emb, W_relT, W_relprop, b_relprop, W_fuse,
                                             W_src, b_src, W_node, b_node, W_g,
                                             src, dst, E, RE,
                                             relfeat, wes, wed, ces, ced, wtu, bucketTot);
    // K2: bases | prep (scores + xbp)
    k_prepb<<<1 + (N + 63) / 64, 256, 0, stream>>>(bucketTot, bucketBase, cursor, ip0, ip1, E,
                                                   x, wes, wed, ces, ced,
                                                   es0, es1, ed0, ed1, xbp, N);
    // K3: cscatter | mm
    k_scmm<<<NCB + 2 * MB, 256, 0, stream>>>(src, dst, E, RE, cursor, pairs0, pairs1, svals,
                                             xbp, gx, wts, b_src, MB, N);

    k_fine<<<dim3(NBUCK, 3), 512, 0, stream>>>(pairs0, pairs1, svals, bucketBase,
                                               ip0, ip1, srcs0, srcs1, xbp, gx, N);

    k_agg<<<(N + 7) / 8, 256, 0, stream>>>(ip0, srcs0, ip1, srcs1, gx,
                                           es0, es1, ed0, ed1, relfeat, fubp, hgbp, N);

    k_fin<<<MB, 256, 0, stream>>>(hgbp, xbp, wts + 3 * 16384, wts + 2 * 16384,
                                  b_g, b_node, fubp, resid_w, scale_w, out, N);
}

// Round 14
// 487.020 us; speedup vs baseline: 1.0383x; 1.0383x over previous
//
#include <hip/hip_runtime.h>
#include <cstddef>

#define NEG_SLOPE 0.2f

typedef __attribute__((ext_vector_type(8))) short bf16x8;
typedef __attribute__((ext_vector_type(4))) float f32x4;

__device__ __forceinline__ float leaky(float v) { return v >= 0.f ? v : NEG_SLOPE * v; }

__device__ __forceinline__ unsigned int bfpack(float a, float b) {
    unsigned int ua = __float_as_uint(a);
    ua += 0x7fffu + ((ua >> 16) & 1u);
    unsigned int ub = __float_as_uint(b);
    ub += 0x7fffu + ((ub >> 16) & 1u);
    return (ua >> 16) | (ub & 0xffff0000u);
}
__device__ __forceinline__ float bflo(unsigned int u) { return __uint_as_float(u << 16); }
__device__ __forceinline__ float bfhi(unsigned int u) { return __uint_as_float(u & 0xffff0000u); }
__device__ __forceinline__ float bfs(unsigned short u) { return __uint_as_float(((unsigned int)u) << 16); }

#define NCB 192   // coarse count/scatter blocks

// ================= K1: small-constants (b==0) | weight transpose (b in [1,64]) | coarse count (b>=65) =================
__global__ __launch_bounds__(512) void k_init(const float* __restrict__ rel_emb, const float* __restrict__ W_relT,
                                              const float* __restrict__ W_relprop, const float* __restrict__ b_relprop,
                                              const float* __restrict__ W_fuse, const float* __restrict__ W_src,
                                              const float* __restrict__ b_src, const float* __restrict__ W_node,
                                              const float* __restrict__ b_node, const float* __restrict__ W_g,
                                              const int* __restrict__ src, const int* __restrict__ dst,
                                              int E, int RE,
                                              float* __restrict__ relfeat, float* __restrict__ wes,
                                              float* __restrict__ wed, float* __restrict__ ces, float* __restrict__ ced,
                                              unsigned int* __restrict__ wt, int* __restrict__ bucketTot) {
    __shared__ float av[512];
    __shared__ float rp[2][128];
    __shared__ int h0[256], h1[256], h2[256];
    int b = blockIdx.x;
    int t = threadIdx.x;
    if (b == 0) {
        {
            int r = t >> 8, m = t & 255;
            float acc = 0.f;
            const float* re = rel_emb + r * 64;
            const float* w = W_relT + (size_t)r * 16384 + m;
            #pragma unroll 8
            for (int k = 0; k < 64; ++k) acc += re[k] * w[(size_t)k * 256];
            av[t] = acc;
        }
        if (t < 256) {
            int r = t >> 7, m = t & 127;
            float acc = b_relprop[t];
            const float* re = rel_emb + r * 64;
            const float* w = W_relprop + (size_t)r * 8192 + m;
            #pragma unroll 8
            for (int k = 0; k < 64; ++k) acc += re[k] * w[(size_t)k * 128];
            rp[r][m] = acc;
        }
        __syncthreads();
        if (t < 256) {
            int r = t >> 7, h = (t >> 5) & 3, d = t & 31;
            float acc = 0.f;
            const float* w = W_fuse + ((size_t)(r * 4 + h) * 32) * 32 + d;
            #pragma unroll
            for (int k = 0; k < 32; ++k) acc += rp[r][h * 32 + k] * w[(size_t)k * 32];
            relfeat[t] = acc;
        }
        for (int idx = t; idx < 2048; idx += 512) {
            int which = idx >> 10, rem = idx & 1023;
            int r = rem >> 9, h = (rem >> 7) & 3, c = rem & 127;
            const float* W = which ? W_node : (W_src + (size_t)r * 16384);
            const float* a = av + r * 256 + h * 64 + which * 32;
            float acc = 0.f;
            #pragma unroll
            for (int d = 0; d < 32; ++d) acc += W[(size_t)c * 128 + h * 32 + d] * a[d];
            (which ? wed : wes)[rem] = acc;
        }
        if (t < 16) {
            int which = t >> 3, r = (t >> 2) & 1, h = t & 3;
            const float* bb = which ? b_node : (b_src + r * 128);
            const float* a = av + r * 256 + h * 64 + which * 32;
            float acc = 0.f;
            #pragma unroll
            for (int d = 0; d < 32; ++d) acc += bb[h * 32 + d] * a[d];
            (which ? ced : ces)[r * 4 + h] = acc;
        }
    } else if (b <= 64) {
        int idx = (b - 1) * 512 + t;   // 4*128*64 = 32768
        int mat = idx >> 13, rem = idx & 8191;
        int nrow = rem >> 6, kp = rem & 63;
        const float* W = mat < 2 ? W_src + (size_t)mat * 16384 : (mat == 2 ? W_node : W_g);
        wt[idx] = bfpack(W[(size_t)(2 * kp) * 128 + nrow], W[(size_t)(2 * kp + 1) * 128 + nrow]);
    } else {
        if (t < 256) { h0[t] = 0; h1[t] = 0; h2[t] = 0; }
        __syncthreads();
        int cb = b - 65;
        int chunk = (RE + NCB - 1) / NCB;
        int lo = cb * chunk, hi = min(lo + chunk, RE);
        for (int i = lo + t; i < hi; i += 512) {
            int d = dst[i], s = src[i];
            atomicAdd((i < E ? h0 : h1) + (d >> 9), 1);
            atomicAdd(&h2[s >> 9], 1);
        }
        __syncthreads();
        if (t < 256) {
            if (h0[t]) atomicAdd(&bucketTot[t], h0[t]);
            if (h1[t]) atomicAdd(&bucketTot[256 + t], h1[t]);
            if (h2[t]) atomicAdd(&bucketTot[512 + t], h2[t]);
        }
    }
}

// ================= K2: bucket-scan (b==0) | prep scores + gx xb section (b>=1) =================
__global__ __launch_bounds__(256) void k_prepb(const int* __restrict__ bucketTot,
                                               int* __restrict__ bucketBase, int* __restrict__ cursor,
                                               int* __restrict__ ip0, int* __restrict__ ip1, int E,
                                               const float* __restrict__ x,
                                               const float* __restrict__ wes, const float* __restrict__ wed,
                                               const float* __restrict__ ces, const float* __restrict__ ced,
                                               float* __restrict__ es0, float* __restrict__ es1,
                                               float* __restrict__ ed0, float* __restrict__ ed1,
                                               unsigned int* __restrict__ gx, int n) {
    __shared__ float xs[64 * 132];
    int tid = threadIdx.x;
    if (blockIdx.x == 0) {
        __shared__ int sc[256];
        int t = tid;
        for (int j = 0; j < 3; ++j) {
            int v = bucketTot[j * 256 + t];
            sc[t] = v;
            __syncthreads();
            for (int off = 1; off < 256; off <<= 1) {
                int tmp = (t >= off) ? sc[t - off] : 0;
                __syncthreads();
                sc[t] += tmp;
                __syncthreads();
            }
            int excl = sc[t] - v;
            bucketBase[j * 257 + t] = excl;
            if (t == 255) bucketBase[j * 257 + 256] = sc[255];
            cursor[j * 256 + t] = excl;
            __syncthreads();
        }
        if (t == 0) { ip0[n] = E; ip1[n] = E; }
        return;
    }
    int nb0 = (blockIdx.x - 1) * 64;
    for (int i = tid; i < 64 * 32; i += 256) {
        int row = i >> 5, c4 = i & 31;
        float4 v = make_float4(0.f, 0.f, 0.f, 0.f);
        if (nb0 + row < n) v = *(const float4*)(x + (size_t)(nb0 + row) * 128 + c4 * 4);
        *(float4*)(xs + row * 132 + c4 * 4) = v;
    }
    __syncthreads();
    for (int i = tid; i < 64 * 64; i += 256) {
        int row = i >> 6, c2 = i & 63;
        int gr = nb0 + row;
        if (gr < n)
            gx[(size_t)gr * 192 + 128 + c2] = bfpack(xs[row * 132 + 2 * c2], xs[row * 132 + 2 * c2 + 1]);
    }
    int node = tid >> 2;
    int gn = nb0 + node;
    if (gn >= n) return;
    #pragma unroll
    for (int q = 0; q < 4; ++q) {
        int j = (tid & 3) + q * 4;          // j = which*8 + r*4 + h
        int which = j >> 3, r = (j >> 2) & 1, h = j & 3;
        const float* w = (which ? wed : wes) + r * 512 + h * 128;
        float acc = (which ? ced : ces)[r * 4 + h];
        #pragma unroll 16
        for (int d = 0; d < 128; ++d) acc += xs[node * 132 + d] * w[d];
        float* outp = which ? (r ? ed1 : ed0) : (r ? es1 : es0);
        outp[(size_t)gn * 4 + h] = acc;
    }
}

// ================= K3: coarse scatter (b<NCB, packed) | dual-relation MFMA GEMM (b>=NCB) =================
__global__ __launch_bounds__(256) void k_scmm(const int* __restrict__ src, const int* __restrict__ dst,
                                              int E, int RE, int* __restrict__ cursor,
                                              unsigned int* __restrict__ pairs0, unsigned int* __restrict__ pairs1,
                                              unsigned short* __restrict__ svals,
                                              unsigned int* __restrict__ gx,
                                              const unsigned short* __restrict__ wts,
                                              const float* __restrict__ b_src, int MB, int n) {
    if (blockIdx.x < NCB) {
        __shared__ int h0[256], h1[256], h2[256];
        __shared__ int c0[256], c1[256], c2[256];
        int t = threadIdx.x;
        h0[t] = 0; h1[t] = 0; h2[t] = 0;
        __syncthreads();
        int chunk = (RE + NCB - 1) / NCB;
        int lo = blockIdx.x * chunk, hi = min(lo + chunk, RE);
        for (int i = lo + t; i < hi; i += 256) {
            int d = dst[i], s = src[i];
            atomicAdd((i < E ? h0 : h1) + (d >> 9), 1);
            atomicAdd(&h2[s >> 9], 1);
        }
        __syncthreads();
        if (h0[t]) c0[t] = atomicAdd(&cursor[t], h0[t]);
        if (h1[t]) c1[t] = atomicAdd(&cursor[256 + t], h1[t]);
        if (h2[t]) c2[t] = atomicAdd(&cursor[512 + t], h2[t]);
        __syncthreads();
        for (int i = lo + t; i < hi; i += 256) {
            int d = dst[i], s = src[i];
            unsigned int packed = ((unsigned)(d & 511) << 23) | (unsigned)s;
            if (i < E) {
                int pos = atomicAdd(&c0[d >> 9], 1);
                pairs0[pos] = packed;
            } else {
                int pos = atomicAdd(&c1[d >> 9], 1);
                pairs1[pos] = packed;
            }
            int pos2 = atomicAdd(&c2[s >> 9], 1);
            svals[pos2] = (unsigned short)(s & 511);
        }
        return;
    }
    int q = blockIdx.x - NCB;
    int rel = q / MB, mb = q % MB;
    const unsigned short* wT = wts + (size_t)rel * 16384;
    const float* bias = b_src + rel * 128;
    int wid = threadIdx.x >> 6, lane = threadIdx.x & 63;
    int l15 = lane & 15, g = lane >> 4;
    int m0 = mb * 128 + wid * 32;
    const unsigned short* Au = (const unsigned short*)gx;   // xb at row*384 + 256
    f32x4 acc[2][8];
    #pragma unroll
    for (int mt = 0; mt < 2; ++mt)
        #pragma unroll
        for (int nt = 0; nt < 8; ++nt)
            #pragma unroll
            for (int r = 0; r < 4; ++r) acc[mt][nt][r] = 0.f;
    #pragma unroll
    for (int t = 0; t < 4; ++t) {
        bf16x8 a0 = *(const bf16x8*)(Au + (size_t)(m0 + l15) * 384 + 256 + t * 32 + g * 8);
        bf16x8 a1 = *(const bf16x8*)(Au + (size_t)(m0 + 16 + l15) * 384 + 256 + t * 32 + g * 8);
        #pragma unroll
        for (int nt = 0; nt < 8; ++nt) {
            bf16x8 b = *(const bf16x8*)(wT + (size_t)(nt * 16 + l15) * 128 + t * 32 + g * 8);
            acc[0][nt] = __builtin_amdgcn_mfma_f32_16x16x32_bf16(a0, b, acc[0][nt], 0, 0, 0);
            acc[1][nt] = __builtin_amdgcn_mfma_f32_16x16x32_bf16(a1, b, acc[1][nt], 0, 0, 0);
        }
    }
    #pragma unroll
    for (int mt = 0; mt < 2; ++mt)
        #pragma unroll
        for (int nt = 0; nt < 8; ++nt) {
            int col = nt * 16 + l15;
            float bv = bias[col];
            #pragma unroll
            for (int r = 0; r < 4; ++r) {
                int row = m0 + mt * 16 + g * 4 + r;
                float v = acc[mt][nt][r] + bv;
                float vp = __shfl_xor(v, 1);
                if (!(l15 & 1) && row < n)
                    gx[(size_t)row * 192 + rel * 64 + (col >> 1)] = bfpack(v, vp);
            }
        }
}

// ---------- stage 4 (3 jobs): per-bucket fine sort (r=0,1) + src out-degree -> rsdo (r=2) ----------
__global__ __launch_bounds__(512) void k_fine(const unsigned int* __restrict__ pairs0,
                                              const unsigned int* __restrict__ pairs1,
                                              const unsigned short* __restrict__ svals,
                                              const int* __restrict__ bucketBase,
                                              int* __restrict__ ip0, int* __restrict__ ip1,
                                              int* __restrict__ srcs0, int* __restrict__ srcs1,
                                              float* __restrict__ rsdo, int N) {
    int r = blockIdx.y;
    int b = blockIdx.x;
    __shared__ int hist[512];
    int t = threadIdx.x;
    hist[t] = 0;
    __syncthreads();
    if (r == 2) {   // src out-degree histogram
        int ebase = bucketBase[2 * 257 + b], eend = bucketBase[2 * 257 + b + 1];
        for (int k = ebase + t; k < eend; k += 512)
            atomicAdd(&hist[svals[k]], 1);
        __syncthreads();
        int node = (b << 9) + t;
        if (node < N) rsdo[node] = rsqrtf(fmaxf((float)hist[t], 1.f));
        return;
    }
    const unsigned int* pairs = r ? pairs1 : pairs0;
    int* ip = r ? ip1 : ip0;
    int* srcs = r ? srcs1 : srcs0;
    int ebase = bucketBase[r * 257 + b], eend = bucketBase[r * 257 + b + 1];
    for (int k = ebase + t; k < eend; k += 512)
        atomicAdd(&hist[pairs[k] >> 23], 1);
    __syncthreads();
    int v = hist[t];
    for (int off = 1; off < 512; off <<= 1) {
        int tmp = (t >= off) ? hist[t - off] : 0;
        __syncthreads();
        hist[t] += tmp;
        __syncthreads();
    }
    int excl = hist[t] - v;
    int node = (b << 9) + t;
    if (node < N) ip[node] = ebase + excl;
    __syncthreads();
    hist[t] = ebase + excl;  // reuse as scatter cursor
    __syncthreads();
    for (int k = ebase + t; k < eend; k += 512) {
        unsigned int p = pairs[k];
        int pos = atomicAdd(&hist[p >> 23], 1);
        srcs[pos] = (int)(p & 0x7FFFFFu);
    }
}

// ---------- CSR gather-aggregate: TWO nodes per wave (32 lanes, 4 ch/lane), uint2 gathers ----------
__global__ __launch_bounds__(256) void k_agg(const int* __restrict__ ip0, const int* __restrict__ srcs0,
                                             const int* __restrict__ ip1, const int* __restrict__ srcs1,
                                             const unsigned int* __restrict__ gx,
                                             const float* __restrict__ es0, const float* __restrict__ es1,
                                             const float* __restrict__ ed0, const float* __restrict__ ed1,
                                             const float* __restrict__ rsdo,
                                             const float* __restrict__ relfeat,
                                             unsigned int* __restrict__ fubp, unsigned int* __restrict__ hgbp, int n) {
    int node = blockIdx.x * 8 + (threadIdx.x >> 5);   // one node per 32-lane half-wave
    if (node >= n) return;
    int l = threadIdx.x & 31;                          // channels 4l .. 4l+3
    int h = l >> 3;
    float ed0v = ed0[(size_t)node * 4 + h];
    float ed1v = ed1[(size_t)node * 4 + h];
    float aU0[4] = {0.f, 0.f, 0.f, 0.f};
    float aU1[4] = {0.f, 0.f, 0.f, 0.f};
    float aH[4]  = {0.f, 0.f, 0.f, 0.f};
    float s0 = 0.f, s1 = 0.f;
    int b0 = ip0[node], e0 = ip0[node + 1];
    #pragma unroll 2
    for (int k = b0; k < e0; ++k) {
        int s = srcs0[k];
        float ex = __expf(leaky(es0[(size_t)s * 4 + h] + ed0v));
        float rs = rsdo[s];
        size_t base = (size_t)s * 192;
        uint2 fv = *(const uint2*)(gx + base + 2 * l);
        uint2 xv = *(const uint2*)(gx + base + 128 + 2 * l);
        aU0[0] += ex * bflo(fv.x); aU0[1] += ex * bfhi(fv.x);
        aU0[2] += ex * bflo(fv.y); aU0[3] += ex * bfhi(fv.y);
        aH[0] += rs * bflo(xv.x); aH[1] += rs * bfhi(xv.x);
        aH[2] += rs * bflo(xv.y); aH[3] += rs * bfhi(xv.y);
        s0 += ex;
    }
    int b1 = ip1[node], e1 = ip1[node + 1];
    #pragma unroll 2
    for (int k = b1; k < e1; ++k) {
        int s = srcs1[k];
        float ex = __expf(leaky(es1[(size_t)s * 4 + h] + ed1v));
        float rs = rsdo[s];
        size_t base = (size_t)s * 192;
        uint2 fv = *(const uint2*)(gx + base + 64 + 2 * l);
        uint2 xv = *(const uint2*)(gx + base + 128 + 2 * l);
        aU1[0] += ex * bflo(fv.x); aU1[1] += ex * bfhi(fv.x);
        aU1[2] += ex * bflo(fv.y); aU1[3] += ex * bfhi(fv.y);
        aH[0] += rs * bflo(xv.x); aH[1] += rs * bfhi(xv.x);
        aH[2] += rs * bflo(xv.y); aH[3] += rs * bfhi(xv.y);
        s1 += ex;
    }
    float i0 = 1.f / (s0 + 1e-9f), i1 = 1.f / (s1 + 1e-9f);
    float f0[4], f1[4];
    #pragma unroll
    for (int c = 0; c < 4; ++c) {
        f0[c] = fmaxf(aU0[c] * i0, 0.f);
        f1[c] = fmaxf(aU1[c] * i1, 0.f);
    }
    float sc0 = 0.f, sc1 = 0.f;
    #pragma unroll
    for (int c = 0; c < 4; ++c) {
        sc0 += f0[c] * relfeat[4 * l + c];
        sc1 += f1[c] * relfeat[128 + 4 * l + c];
    }
    #pragma unroll
    for (int m = 1; m < 8; m <<= 1) {     // reduce over the 8-lane head group
        sc0 += __shfl_xor(sc0, m, 64);
        sc1 += __shfl_xor(sc1, m, 64);
    }
    sc0 = leaky(sc0); sc1 = leaky(sc1);
    float mx = fmaxf(sc0, sc1);
    float p0 = __expf(sc0 - mx), p1 = __expf(sc1 - mx);
    float inv = 1.f / (p0 + p1);
    p0 *= inv; p1 *= inv;
    float rv = rsqrtf(fmaxf((float)((e0 - b0) + (e1 - b1)), 1.f));
    uint2 fo, ho;
    fo.x = bfpack(p0 * f0[0] + p1 * f1[0], p0 * f0[1] + p1 * f1[1]);
    fo.y = bfpack(p0 * f0[2] + p1 * f1[2], p0 * f0[3] + p1 * f1[3]);
    ho.x = bfpack(aH[0] * rv, aH[1] * rv);
    ho.y = bfpack(aH[2] * rv, aH[3] * rv);
    *(uint2*)(fubp + (size_t)node * 64 + 2 * l) = fo;
    *(uint2*)(hgbp + (size_t)node * 64 + 2 * l) = ho;
}

// ---------- final: two MFMA GEMMs (hgb @ Wg, xb @ Wn) + fusion epilogue ----------
__global__ __launch_bounds__(256) void k_fin(const unsigned int* __restrict__ hgbp,
                                             const unsigned int* __restrict__ gx,
                                             const unsigned short* __restrict__ wtg,
                                             const unsigned short* __restrict__ wtn,
                                             const float* __restrict__ bg, const float* __restrict__ bn,
                                             const unsigned int* __restrict__ fubp,
                                             const float* __restrict__ residual_w, const float* __restrict__ scale_w,
                                             float* __restrict__ out, int n) {
    int wid = threadIdx.x >> 6, lane = threadIdx.x & 63;
    int l15 = lane & 15, g = lane >> 4;
    int m0 = blockIdx.x * 128 + wid * 32;
    const unsigned short* Hu = (const unsigned short*)hgbp;
    const unsigned short* Xu = (const unsigned short*)gx;   // xb at row*384 + 256
    const unsigned short* Fu = (const unsigned short*)fubp;
    f32x4 accn[2][8], accg[2][8];
    #pragma unroll
    for (int mt = 0; mt < 2; ++mt)
        #pragma unroll
        for (int nt = 0; nt < 8; ++nt)
            #pragma unroll
            for (int r = 0; r < 4; ++r) { accn[mt][nt][r] = 0.f; accg[mt][nt][r] = 0.f; }
    #pragma unroll
    for (int t = 0; t < 4; ++t) {
        bf16x8 a0 = *(const bf16x8*)(Xu + (size_t)(m0 + l15) * 384 + 256 + t * 32 + g * 8);
        bf16x8 a1 = *(const bf16x8*)(Xu + (size_t)(m0 + 16 + l15) * 384 + 256 + t * 32 + g * 8);
        #pragma unroll
        for (int nt = 0; nt < 8; ++nt) {
            bf16x8 b = *(const bf16x8*)(wtn + (size_t)(nt * 16 + l15) * 128 + t * 32 + g * 8);
            accn[0][nt] = __builtin_amdgcn_mfma_f32_16x16x32_bf16(a0, b, accn[0][nt], 0, 0, 0);
            accn[1][nt] = __builtin_amdgcn_mfma_f32_16x16x32_bf16(a1, b, accn[1][nt], 0, 0, 0);
        }
    }
    #pragma unroll
    for (int t = 0; t < 4; ++t) {
        bf16x8 a0 = *(const bf16x8*)(Hu + (size_t)(m0 + l15) * 128 + t * 32 + g * 8);
        bf16x8 a1 = *(const bf16x8*)(Hu + (size_t)(m0 + 16 + l15) * 128 + t * 32 + g * 8);
        #pragma unroll
        for (int nt = 0; nt < 8; ++nt) {
            bf16x8 b = *(const bf16x8*)(wtg + (size_t)(nt * 16 + l15) * 128 + t * 32 + g * 8);
            accg[0][nt] = __builtin_amdgcn_mfma_f32_16x16x32_bf16(a0, b, accg[0][nt], 0, 0, 0);
            accg[1][nt] = __builtin_amdgcn_mfma_f32_16x16x32_bf16(a1, b, accg[1][nt], 0, 0, 0);
        }
    }
    float beta = 1.f / (1.f + __expf(-residual_w[0]));
    float av = 1.f / (1.f + __expf(-scale_w[0]));
    #pragma unroll
    for (int mt = 0; mt < 2; ++mt)
        #pragma unroll
        for (int nt = 0; nt < 8; ++nt) {
            int col = nt * 16 + l15;
            float bnv = bn[col], bgv = bg[col];
            #pragma unroll
            for (int r = 0; r < 4; ++r) {
                int row = m0 + mt * 16 + g * 4 + r;
                if (row < n) {
                    float fu = bfs(Fu[(size_t)row * 128 + col]);
                    float fd = accn[mt][nt][r] + bnv;
                    float f = beta * fu + (1.f - beta) * fd;
                    float nl = fmaxf(accg[mt][nt][r] + bgv, 0.f);
                    out[(size_t)row * 128 + col] = av * f + (1.f - av) * nl;
                }
            }
        }
}

extern "C" void kernel_launch(void* const* d_in, const int* in_sizes, int n_in,
                              void* d_out, int out_size, void* d_ws, size_t ws_size,
                              hipStream_t stream) {
    const float* x         = (const float*)d_in[0];
    const int*   src       = (const int*)d_in[1];
    const int*   dst       = (const int*)d_in[2];
    const float* rel_emb   = (const float*)d_in[3];
    const float* W_node    = (const float*)d_in[4];
    const float* b_node    = (const float*)d_in[5];
    const float* W_src     = (const float*)d_in[6];
    const float* b_src     = (const float*)d_in[7];
    const float* W_relT    = (const float*)d_in[8];
    const float* W_relprop = (const float*)d_in[9];
    const float* b_relprop = (const float*)d_in[10];
    const float* W_fuse    = (const float*)d_in[11];
    const float* resid_w   = (const float*)d_in[12];
    const float* scale_w   = (const float*)d_in[13];
    const float* W_g       = (const float*)d_in[14];
    const float* b_g       = (const float*)d_in[15];
    float* out = (float*)d_out;

    const int N = in_sizes[0] / 128;
    const int RE = in_sizes[1];
    const int E = RE / 2;
    const int Npad = (N + 127) & ~127;
    const int NBUCK = (N + 511) >> 9;
    const int MB = Npad / 128;

    // workspace (~144 MB at N=1e5, E=1e6)
    float* ws = (float*)d_ws;
    size_t o = 0;
    unsigned int* fubp = (unsigned int*)(ws + o); o += (size_t)Npad * 64;   // fused bf16; aliased by sort scratch early
    unsigned int* gx   = (unsigned int*)(ws + o); o += (size_t)Npad * 192;  // fs0|fs1|xb interleaved (768B rows)
    unsigned int* hgbp = (unsigned int*)(ws + o); o += (size_t)Npad * 64;   // bf16 hg*rsdi
    float* es0  = ws + o; o += (size_t)N * 4;
    float* es1  = ws + o; o += (size_t)N * 4;
    float* ed0  = ws + o; o += (size_t)N * 4;
    float* ed1  = ws + o; o += (size_t)N * 4;
    float* rsdo = ws + o; o += N;
    unsigned int* wtu = (unsigned int*)(ws + o); o += 32768;  // bf16 W^T x4 mats
    float* relfeat = ws + o; o += 256;
    float* wes  = ws + o; o += 1024;
    float* wed  = ws + o; o += 1024;
    float* ces  = ws + o; o += 16;
    float* ced  = ws + o; o += 16;
    int* ip0  = (int*)(ws + o); o += N + 1;
    int* ip1  = (int*)(ws + o); o += N + 1;
    int* srcs0 = (int*)(ws + o); o += E;
    int* srcs1 = (int*)(ws + o); o += E;
    int* bucketTot  = (int*)(ws + o); o += 768;
    int* bucketBase = (int*)(ws + o); o += 771;
    int* cursor     = (int*)(ws + o); o += 768;
    // transient sort scratch aliased into fubp region (12 MB <= Npad*256B)
    unsigned int* pairs0 = (unsigned int*)fubp;                 // E uints
    unsigned int* pairs1 = pairs0 + (size_t)E;                  // E uints
    unsigned short* svals = (unsigned short*)(pairs1 + (size_t)E);  // RE ushorts

    const unsigned short* wts = (const unsigned short*)wtu;  // mat m at wts + m*16384

    hipMemsetAsync(bucketTot, 0, 768 * sizeof(int), stream);

    // K1: small | twt | count
    k_init<<<1 + 64 + NCB, 512, 0, stream>>>(rel_emb, W_relT, W_relprop, b_relprop, W_fuse,
                                             W_src, b_src, W_node, b_node, W_g,
                                             src, dst, E, RE,
                                             relfeat, wes, wed, ces, ced, wtu, bucketTot);
    // K2: bases | prep (scores + gx xb section)
    k_prepb<<<1 + (N + 63) / 64, 256, 0, stream>>>(bucketTot, bucketBase, cursor, ip0, ip1, E,
                                                   x, wes, wed, ces, ced,
                                                   es0, es1, ed0, ed1, gx, N);
    // K3: cscatter | mm
    k_scmm<<<NCB + 2 * MB, 256, 0, stream>>>(src, dst, E, RE, cursor, pairs0, pairs1, svals,
                                             gx, wts, b_src, MB, N);

    k_fine<<<dim3(NBUCK, 3), 512, 0, stream>>>(pairs0, pairs1, svals, bucketBase,
                                               ip0, ip1, srcs0, srcs1, rsdo, N);

    k_agg<<<(N + 7) / 8, 256, 0, stream>>>(ip0, srcs0, ip1, srcs1, gx,
                                           es0, es1, ed0, ed1, rsdo, relfeat, fubp, hgbp, N);

    k_fin<<<MB, 256, 0, stream>>>(hgbp, gx, wts + 3 * 16384, wts + 2 * 16384,
                                  b_g, b_node, fubp, resid_w, scale_w, out, N);
}

// Round 16
// 375.330 us; speedup vs baseline: 1.3473x; 1.2976x over previous
//
#include <hip/hip_runtime.h>
#include <cstddef>

#define NEG_SLOPE 0.2f

typedef __attribute__((ext_vector_type(8))) short bf16x8;
typedef __attribute__((ext_vector_type(4))) float f32x4;

__device__ __forceinline__ float leaky(float v) { return v >= 0.f ? v : NEG_SLOPE * v; }

__device__ __forceinline__ unsigned int bfpack(float a, float b) {
    unsigned int ua = __float_as_uint(a);
    ua += 0x7fffu + ((ua >> 16) & 1u);
    unsigned int ub = __float_as_uint(b);
    ub += 0x7fffu + ((ub >> 16) & 1u);
    return (ua >> 16) | (ub & 0xffff0000u);
}
__device__ __forceinline__ float bflo(unsigned int u) { return __uint_as_float(u << 16); }
__device__ __forceinline__ float bfhi(unsigned int u) { return __uint_as_float(u & 0xffff0000u); }
__device__ __forceinline__ float bfs(unsigned short u) { return __uint_as_float(((unsigned int)u) << 16); }

#define NCB 192   // coarse count/scatter blocks

// ===== K1: small-consts (b==0) | W^T transpose (b in [1,64]) | coarse count (b in [65,64+NCB]) | x->bf16 (rest) =====
__global__ __launch_bounds__(512) void k_init(const float* __restrict__ rel_emb, const float* __restrict__ W_relT,
                                              const float* __restrict__ W_relprop, const float* __restrict__ b_relprop,
                                              const float* __restrict__ W_fuse, const float* __restrict__ W_src,
                                              const float* __restrict__ b_src, const float* __restrict__ W_node,
                                              const float* __restrict__ b_node, const float* __restrict__ W_g,
                                              const int* __restrict__ src, const int* __restrict__ dst,
                                              const float* __restrict__ x,
                                              int E, int RE,
                                              float* __restrict__ relfeat, unsigned short* __restrict__ wscb,
                                              float* __restrict__ ces, float* __restrict__ ced,
                                              unsigned int* __restrict__ wt, int* __restrict__ bucketTot,
                                              unsigned int* __restrict__ gx, int n) {
    __shared__ float av[512];
    __shared__ float rp[2][128];
    __shared__ int h0[256], h1[256], h2[256];
    int b = blockIdx.x;
    int t = threadIdx.x;
    if (b == 0) {
        {
            int r = t >> 8, m = t & 255;
            float acc = 0.f;
            const float* re = rel_emb + r * 64;
            const float* w = W_relT + (size_t)r * 16384 + m;
            #pragma unroll 8
            for (int k = 0; k < 64; ++k) acc += re[k] * w[(size_t)k * 256];
            av[t] = acc;
        }
        if (t < 256) {
            int r = t >> 7, m = t & 127;
            float acc = b_relprop[t];
            const float* re = rel_emb + r * 64;
            const float* w = W_relprop + (size_t)r * 8192 + m;
            #pragma unroll 8
            for (int k = 0; k < 64; ++k) acc += re[k] * w[(size_t)k * 128];
            rp[r][m] = acc;
        }
        __syncthreads();
        if (t < 256) {
            int r = t >> 7, h = (t >> 5) & 3, d = t & 31;
            float acc = 0.f;
            const float* w = W_fuse + ((size_t)(r * 4 + h) * 32) * 32 + d;
            #pragma unroll
            for (int k = 0; k < 32; ++k) acc += rp[r][h * 32 + k] * w[(size_t)k * 32];
            relfeat[t] = acc;
        }
        // score-projection vectors -> bf16 wscb[j][k], j = which*8 + r*4 + h
        for (int idx = t; idx < 2048; idx += 512) {
            int which = idx >> 10, rem = idx & 1023;
            int r = rem >> 9, h = (rem >> 7) & 3, c = rem & 127;
            const float* W = which ? W_node : (W_src + (size_t)r * 16384);
            const float* a = av + r * 256 + h * 64 + which * 32;
            float acc = 0.f;
            #pragma unroll
            for (int d = 0; d < 32; ++d) acc += W[(size_t)c * 128 + h * 32 + d] * a[d];
            int j = which * 8 + r * 4 + h;
            wscb[j * 128 + c] = (unsigned short)(bfpack(acc, 0.f) & 0xffffu);
        }
        if (t < 16) {
            int which = t >> 3, r = (t >> 2) & 1, h = t & 3;
            const float* bb = which ? b_node : (b_src + r * 128);
            const float* a = av + r * 256 + h * 64 + which * 32;
            float acc = 0.f;
            #pragma unroll
            for (int d = 0; d < 32; ++d) acc += bb[h * 32 + d] * a[d];
            (which ? ced : ces)[r * 4 + h] = acc;
        }
    } else if (b <= 64) {
        int idx = (b - 1) * 512 + t;   // 4*128*64 = 32768
        int mat = idx >> 13, rem = idx & 8191;
        int nrow = rem >> 6, kp = rem & 63;
        const float* W = mat < 2 ? W_src + (size_t)mat * 16384 : (mat == 2 ? W_node : W_g);
        wt[idx] = bfpack(W[(size_t)(2 * kp) * 128 + nrow], W[(size_t)(2 * kp + 1) * 128 + nrow]);
    } else if (b <= 64 + NCB) {
        if (t < 256) { h0[t] = 0; h1[t] = 0; h2[t] = 0; }
        __syncthreads();
        int cb = b - 65;
        int chunk = (RE + NCB - 1) / NCB;
        int lo = cb * chunk, hi = min(lo + chunk, RE);
        for (int i = lo + t; i < hi; i += 512) {
            int d = dst[i], s = src[i];
            atomicAdd((i < E ? h0 : h1) + (d >> 9), 1);
            atomicAdd(&h2[s >> 9], 1);
        }
        __syncthreads();
        if (t < 256) {
            if (h0[t]) atomicAdd(&bucketTot[t], h0[t]);
            if (h1[t]) atomicAdd(&bucketTot[256 + t], h1[t]);
            if (h2[t]) atomicAdd(&bucketTot[512 + t], h2[t]);
        }
    } else {
        // x -> bf16 into gx xb section (128 rows per block)
        int nb0 = (b - 65 - NCB) * 128;
        for (int i = t; i < 128 * 32; i += 512) {
            int row = i >> 5, c4 = i & 31;
            int gr = nb0 + row;
            if (gr < n) {
                float4 v = *(const float4*)(x + (size_t)gr * 128 + c4 * 4);
                uint2 w;
                w.x = bfpack(v.x, v.y);
                w.y = bfpack(v.z, v.w);
                *(uint2*)(gx + (size_t)gr * 192 + 128 + c4 * 2) = w;
            }
        }
    }
}

// ===== K2: bucket-scan -> bases + cursors (1 block) =====
__global__ __launch_bounds__(256) void k_bases(const int* __restrict__ bucketTot,
                                               int* __restrict__ bucketBase, int* __restrict__ cursor,
                                               int* __restrict__ ip0, int* __restrict__ ip1,
                                               int N, int E) {
    __shared__ int sc[256];
    int t = threadIdx.x;
    for (int j = 0; j < 3; ++j) {
        int v = bucketTot[j * 256 + t];
        sc[t] = v;
        __syncthreads();
        for (int off = 1; off < 256; off <<= 1) {
            int tmp = (t >= off) ? sc[t - off] : 0;
            __syncthreads();
            sc[t] += tmp;
            __syncthreads();
        }
        int excl = sc[t] - v;
        bucketBase[j * 257 + t] = excl;
        if (t == 255) bucketBase[j * 257 + 256] = sc[255];
        cursor[j * 256 + t] = excl;
        __syncthreads();
    }
    if (t == 0) { ip0[N] = E; ip1[N] = E; }
}

// ===== K3: coarse scatter (b<NCB, packed) | dual-relation MFMA GEMM + score GEMM (b>=NCB) =====
__global__ __launch_bounds__(256) void k_scmm(const int* __restrict__ src, const int* __restrict__ dst,
                                              int E, int RE, int* __restrict__ cursor,
                                              unsigned int* __restrict__ pairs0, unsigned int* __restrict__ pairs1,
                                              unsigned short* __restrict__ svals,
                                              unsigned int* __restrict__ gx,
                                              const unsigned short* __restrict__ wts,
                                              const unsigned short* __restrict__ wscb,
                                              const float* __restrict__ b_src,
                                              const float* __restrict__ ces, const float* __restrict__ ced,
                                              float* __restrict__ es0, float* __restrict__ es1,
                                              float* __restrict__ ed0, float* __restrict__ ed1,
                                              int MB, int n) {
    if (blockIdx.x < NCB) {
        __shared__ int h0[256], h1[256], h2[256];
        __shared__ int c0[256], c1[256], c2[256];
        int t = threadIdx.x;
        h0[t] = 0; h1[t] = 0; h2[t] = 0;
        __syncthreads();
        int chunk = (RE + NCB - 1) / NCB;
        int lo = blockIdx.x * chunk, hi = min(lo + chunk, RE);
        for (int i = lo + t; i < hi; i += 256) {
            int d = dst[i], s = src[i];
            atomicAdd((i < E ? h0 : h1) + (d >> 9), 1);
            atomicAdd(&h2[s >> 9], 1);
        }
        __syncthreads();
        if (h0[t]) c0[t] = atomicAdd(&cursor[t], h0[t]);
        if (h1[t]) c1[t] = atomicAdd(&cursor[256 + t], h1[t]);
        if (h2[t]) c2[t] = atomicAdd(&cursor[512 + t], h2[t]);
        __syncthreads();
        for (int i = lo + t; i < hi; i += 256) {
            int d = dst[i], s = src[i];
            unsigned int packed = ((unsigned)(d & 511) << 23) | (unsigned)s;
            if (i < E) {
                int pos = atomicAdd(&c0[d >> 9], 1);
                pairs0[pos] = packed;
            } else {
                int pos = atomicAdd(&c1[d >> 9], 1);
                pairs1[pos] = packed;
            }
            int pos2 = atomicAdd(&c2[s >> 9], 1);
            svals[pos2] = (unsigned short)(s & 511);
        }
        return;
    }
    int q = blockIdx.x - NCB;
    int rel = q / MB, mb = q % MB;
    const unsigned short* wT = wts + (size_t)rel * 16384;
    const float* bias = b_src + rel * 128;
    int wid = threadIdx.x >> 6, lane = threadIdx.x & 63;
    int l15 = lane & 15, g = lane >> 4;
    int m0 = mb * 128 + wid * 32;
    const unsigned short* Au = (const unsigned short*)gx;   // xb at row*384 + 256
    f32x4 acc[2][8];
    f32x4 asc[2];
    #pragma unroll
    for (int mt = 0; mt < 2; ++mt) {
        #pragma unroll
        for (int nt = 0; nt < 8; ++nt)
            #pragma unroll
            for (int r = 0; r < 4; ++r) acc[mt][nt][r] = 0.f;
        #pragma unroll
        for (int r = 0; r < 4; ++r) asc[mt][r] = 0.f;
    }
    #pragma unroll
    for (int t = 0; t < 4; ++t) {
        bf16x8 a0 = *(const bf16x8*)(Au + (size_t)(m0 + l15) * 384 + 256 + t * 32 + g * 8);
        bf16x8 a1 = *(const bf16x8*)(Au + (size_t)(m0 + 16 + l15) * 384 + 256 + t * 32 + g * 8);
        #pragma unroll
        for (int nt = 0; nt < 8; ++nt) {
            bf16x8 b = *(const bf16x8*)(wT + (size_t)(nt * 16 + l15) * 128 + t * 32 + g * 8);
            acc[0][nt] = __builtin_amdgcn_mfma_f32_16x16x32_bf16(a0, b, acc[0][nt], 0, 0, 0);
            acc[1][nt] = __builtin_amdgcn_mfma_f32_16x16x32_bf16(a1, b, acc[1][nt], 0, 0, 0);
        }
        if (rel == 0) {
            bf16x8 bs = *(const bf16x8*)(wscb + l15 * 128 + t * 32 + g * 8);
            asc[0] = __builtin_amdgcn_mfma_f32_16x16x32_bf16(a0, bs, asc[0], 0, 0, 0);
            asc[1] = __builtin_amdgcn_mfma_f32_16x16x32_bf16(a1, bs, asc[1], 0, 0, 0);
        }
    }
    #pragma unroll
    for (int mt = 0; mt < 2; ++mt)
        #pragma unroll
        for (int nt = 0; nt < 8; ++nt) {
            int col = nt * 16 + l15;
            float bv = bias[col];
            #pragma unroll
            for (int r = 0; r < 4; ++r) {
                int row = m0 + mt * 16 + g * 4 + r;
                float v = acc[mt][nt][r] + bv;
                float vp = __shfl_xor(v, 1);
                if (!(l15 & 1) && row < n)
                    gx[(size_t)row * 192 + rel * 64 + (col >> 1)] = bfpack(v, vp);
            }
        }
    if (rel == 0) {
        int which = l15 >> 3, rr = (l15 >> 2) & 1, h = l15 & 3;
        float bsc = (which ? ced : ces)[l15 & 7];
        float* outp = which ? (rr ? ed1 : ed0) : (rr ? es1 : es0);
        #pragma unroll
        for (int mt = 0; mt < 2; ++mt)
            #pragma unroll
            for (int r = 0; r < 4; ++r) {
                int row = m0 + mt * 16 + g * 4 + r;
                if (row < n) outp[(size_t)row * 4 + h] = asc[mt][r] + bsc;
            }
    }
}

// ---------- stage 4 (3 jobs): per-bucket fine sort (r=0,1) + src out-degree -> rsdo (r=2) ----------
__global__ __launch_bounds__(512) void k_fine(const unsigned int* __restrict__ pairs0,
                                              const unsigned int* __restrict__ pairs1,
                                              const unsigned short* __restrict__ svals,
                                              const int* __restrict__ bucketBase,
                                              int* __restrict__ ip0, int* __restrict__ ip1,
                                              int* __restrict__ srcs0, int* __restrict__ srcs1,
                                              float* __restrict__ rsdo, int N) {
    int r = blockIdx.y;
    int b = blockIdx.x;
    __shared__ int hist[512];
    int t = threadIdx.x;
    hist[t] = 0;
    __syncthreads();
    if (r == 2) {   // src out-degree histogram
        int ebase = bucketBase[2 * 257 + b], eend = bucketBase[2 * 257 + b + 1];
        for (int k = ebase + t; k < eend; k += 512)
            atomicAdd(&hist[svals[k]], 1);
        __syncthreads();
        int node = (b << 9) + t;
        if (node < N) rsdo[node] = rsqrtf(fmaxf((float)hist[t], 1.f));
        return;
    }
    const unsigned int* pairs = r ? pairs1 : pairs0;
    int* ip = r ? ip1 : ip0;
    int* srcs = r ? srcs1 : srcs0;
    int ebase = bucketBase[r * 257 + b], eend = bucketBase[r * 257 + b + 1];
    for (int k = ebase + t; k < eend; k += 512)
        atomicAdd(&hist[pairs[k] >> 23], 1);
    __syncthreads();
    int v = hist[t];
    for (int off = 1; off < 512; off <<= 1) {
        int tmp = (t >= off) ? hist[t - off] : 0;
        __syncthreads();
        hist[t] += tmp;
        __syncthreads();
    }
    int excl = hist[t] - v;
    int node = (b << 9) + t;
    if (node < N) ip[node] = ebase + excl;
    __syncthreads();
    hist[t] = ebase + excl;  // reuse as scatter cursor
    __syncthreads();
    for (int k = ebase + t; k < eend; k += 512) {
        unsigned int p = pairs[k];
        int pos = atomicAdd(&hist[p >> 23], 1);
        srcs[pos] = (int)(p & 0x7FFFFFu);
    }
}

// ---------- CSR gather-aggregate: TWO nodes per wave (32 lanes, 4 ch/lane), uint2 gathers ----------
__global__ __launch_bounds__(256) void k_agg(const int* __restrict__ ip0, const int* __restrict__ srcs0,
                                             const int* __restrict__ ip1, const int* __restrict__ srcs1,
                                             const unsigned int* __restrict__ gx,
                                             const float* __restrict__ es0, const float* __restrict__ es1,
                                             const float* __restrict__ ed0, const float* __restrict__ ed1,
                                             const float* __restrict__ rsdo,
                                             const float* __restrict__ relfeat,
                                             unsigned int* __restrict__ fubp, unsigned int* __restrict__ hgbp, int n) {
    int node = blockIdx.x * 8 + (threadIdx.x >> 5);   // one node per 32-lane half-wave
    if (node >= n) return;
    int l = threadIdx.x & 31;                          // channels 4l .. 4l+3
    int h = l >> 3;
    float ed0v = ed0[(size_t)node * 4 + h];
    float ed1v = ed1[(size_t)node * 4 + h];
    float aU0[4] = {0.f, 0.f, 0.f, 0.f};
    float aU1[4] = {0.f, 0.f, 0.f, 0.f};
    float aH[4]  = {0.f, 0.f, 0.f, 0.f};
    float s0 = 0.f, s1 = 0.f;
    int b0 = ip0[node], e0 = ip0[node + 1];
    #pragma unroll 2
    for (int k = b0; k < e0; ++k) {
        int s = srcs0[k];
        float ex = __expf(leaky(es0[(size_t)s * 4 + h] + ed0v));
        float rs = rsdo[s];
        size_t base = (size_t)s * 192;
        uint2 fv = *(const uint2*)(gx + base + 2 * l);
        uint2 xv = *(const uint2*)(gx + base + 128 + 2 * l);
        aU0[0] += ex * bflo(fv.x); aU0[1] += ex * bfhi(fv.x);
        aU0[2] += ex * bflo(fv.y); aU0[3] += ex * bfhi(fv.y);
        aH[0] += rs * bflo(xv.x); aH[1] += rs * bfhi(xv.x);
        aH[2] += rs * bflo(xv.y); aH[3] += rs * bfhi(xv.y);
        s0 += ex;
    }
    int b1 = ip1[node], e1 = ip1[node + 1];
    #pragma unroll 2
    for (int k = b1; k < e1; ++k) {
        int s = srcs1[k];
        float ex = __expf(leaky(es1[(size_t)s * 4 + h] + ed1v));
        float rs = rsdo[s];
        size_t base = (size_t)s * 192;
        uint2 fv = *(const uint2*)(gx + base + 64 + 2 * l);
        uint2 xv = *(const uint2*)(gx + base + 128 + 2 * l);
        aU1[0] += ex * bflo(fv.x); aU1[1] += ex * bfhi(fv.x);
        aU1[2] += ex * bflo(fv.y); aU1[3] += ex * bfhi(fv.y);
        aH[0] += rs * bflo(xv.x); aH[1] += rs * bfhi(xv.x);
        aH[2] += rs * bflo(xv.y); aH[3] += rs * bfhi(xv.y);
        s1 += ex;
    }
    float i0 = 1.f / (s0 + 1e-9f), i1 = 1.f / (s1 + 1e-9f);
    float f0[4], f1[4];
    #pragma unroll
    for (int c = 0; c < 4; ++c) {
        f0[c] = fmaxf(aU0[c] * i0, 0.f);
        f1[c] = fmaxf(aU1[c] * i1, 0.f);
    }
    float sc0 = 0.f, sc1 = 0.f;
    #pragma unroll
    for (int c = 0; c < 4; ++c) {
        sc0 += f0[c] * relfeat[4 * l + c];
        sc1 += f1[c] * relfeat[128 + 4 * l + c];
    }
    #pragma unroll
    for (int m = 1; m < 8; m <<= 1) {     // reduce over the 8-lane head group
        sc0 += __shfl_xor(sc0, m, 64);
        sc1 += __shfl_xor(sc1, m, 64);
    }
    sc0 = leaky(sc0); sc1 = leaky(sc1);
    float mx = fmaxf(sc0, sc1);
    float p0 = __expf(sc0 - mx), p1 = __expf(sc1 - mx);
    float inv = 1.f / (p0 + p1);
    p0 *= inv; p1 *= inv;
    float rv = rsqrtf(fmaxf((float)((e0 - b0) + (e1 - b1)), 1.f));
    uint2 fo, ho;
    fo.x = bfpack(p0 * f0[0] + p1 * f1[0], p0 * f0[1] + p1 * f1[1]);
    fo.y = bfpack(p0 * f0[2] + p1 * f1[2], p0 * f0[3] + p1 * f1[3]);
    ho.x = bfpack(aH[0] * rv, aH[1] * rv);
    ho.y = bfpack(aH[2] * rv, aH[3] * rv);
    *(uint2*)(fubp + (size_t)node * 64 + 2 * l) = fo;
    *(uint2*)(hgbp + (size_t)node * 64 + 2 * l) = ho;
}

// ---------- final: two MFMA GEMMs (hgb @ Wg, xb @ Wn) + fusion epilogue ----------
__global__ __launch_bounds__(256) void k_fin(const unsigned int* __restrict__ hgbp,
                                             const unsigned int* __restrict__ gx,
                                             const unsigned short* __restrict__ wtg,
                                             const unsigned short* __restrict__ wtn,
                                             const float* __restrict__ bg, const float* __restrict__ bn,
                                             const unsigned int* __restrict__ fubp,
                                             const float* __restrict__ residual_w, const float* __restrict__ scale_w,
                                             float* __restrict__ out, int n) {
    int wid = threadIdx.x >> 6, lane = threadIdx.x & 63;
    int l15 = lane & 15, g = lane >> 4;
    int m0 = blockIdx.x * 128 + wid * 32;
    const unsigned short* Hu = (const unsigned short*)hgbp;
    const unsigned short* Xu = (const unsigned short*)gx;   // xb at row*384 + 256
    const unsigned short* Fu = (const unsigned short*)fubp;
    f32x4 accn[2][8], accg[2][8];
    #pragma unroll
    for (int mt = 0; mt < 2; ++mt)
        #pragma unroll
        for (int nt = 0; nt < 8; ++nt)
            #pragma unroll
            for (int r = 0; r < 4; ++r) { accn[mt][nt][r] = 0.f; accg[mt][nt][r] = 0.f; }
    #pragma unroll
    for (int t = 0; t < 4; ++t) {
        bf16x8 a0 = *(const bf16x8*)(Xu + (size_t)(m0 + l15) * 384 + 256 + t * 32 + g * 8);
        bf16x8 a1 = *(const bf16x8*)(Xu + (size_t)(m0 + 16 + l15) * 384 + 256 + t * 32 + g * 8);
        #pragma unroll
        for (int nt = 0; nt < 8; ++nt) {
            bf16x8 b = *(const bf16x8*)(wtn + (size_t)(nt * 16 + l15) * 128 + t * 32 + g * 8);
            accn[0][nt] = __builtin_amdgcn_mfma_f32_16x16x32_bf16(a0, b, accn[0][nt], 0, 0, 0);
            accn[1][nt] = __builtin_amdgcn_mfma_f32_16x16x32_bf16(a1, b, accn[1][nt], 0, 0, 0);
        }
    }
    #pragma unroll
    for (int t = 0; t < 4; ++t) {
        bf16x8 a0 = *(const bf16x8*)(Hu + (size_t)(m0 + l15) * 128 + t * 32 + g * 8);
        bf16x8 a1 = *(const bf16x8*)(Hu + (size_t)(m0 + 16 + l15) * 128 + t * 32 + g * 8);
        #pragma unroll
        for (int nt = 0; nt < 8; ++nt) {
            bf16x8 b = *(const bf16x8*)(wtg + (size_t)(nt * 16 + l15) * 128 + t * 32 + g * 8);
            accg[0][nt] = __builtin_amdgcn_mfma_f32_16x16x32_bf16(a0, b, accg[0][nt], 0, 0, 0);
            accg[1][nt] = __builtin_amdgcn_mfma_f32_16x16x32_bf16(a1, b, accg[1][nt], 0, 0, 0);
        }
    }
    float beta = 1.f / (1.f + __expf(-residual_w[0]));
    float av = 1.f / (1.f + __expf(-scale_w[0]));
    #pragma unroll
    for (int mt = 0; mt < 2; ++mt)
        #pragma unroll
        for (int nt = 0; nt < 8; ++nt) {
            int col = nt * 16 + l15;
            float bnv = bn[col], bgv = bg[col];
            #pragma unroll
            for (int r = 0; r < 4; ++r) {
                int row = m0 + mt * 16 + g * 4 + r;
                if (row < n) {
                    float fu = bfs(Fu[(size_t)row * 128 + col]);
                    float fd = accn[mt][nt][r] + bnv;
                    float f = beta * fu + (1.f - beta) * fd;
                    float nl = fmaxf(accg[mt][nt][r] + bgv, 0.f);
                    out[(size_t)row * 128 + col] = av * f + (1.f - av) * nl;
                }
            }
        }
}

extern "C" void kernel_launch(void* const* d_in, const int* in_sizes, int n_in,
                              void* d_out, int out_size, void* d_ws, size_t ws_size,
                              hipStream_t stream) {
    const float* x         = (const float*)d_in[0];
    const int*   src       = (const int*)d_in[1];
    const int*   dst       = (const int*)d_in[2];
    const float* rel_emb   = (const float*)d_in[3];
    const float* W_node    = (const float*)d_in[4];
    const float* b_node    = (const float*)d_in[5];
    const float* W_src     = (const float*)d_in[6];
    const float* b_src     = (const float*)d_in[7];
    const float* W_relT    = (const float*)d_in[8];
    const float* W_relprop = (const float*)d_in[9];
    const float* b_relprop = (const float*)d_in[10];
    const float* W_fuse    = (const float*)d_in[11];
    const float* resid_w   = (const float*)d_in[12];
    const float* scale_w   = (const float*)d_in[13];
    const float* W_g       = (const float*)d_in[14];
    const float* b_g       = (const float*)d_in[15];
    float* out = (float*)d_out;

    const int N = in_sizes[0] / 128;
    const int RE = in_sizes[1];
    const int E = RE / 2;
    const int Npad = (N + 127) & ~127;
    const int NBUCK = (N + 511) >> 9;
    const int MB = Npad / 128;
    const int CVB = (N + 127) / 128;

    // workspace (~144 MB at N=1e5, E=1e6)
    float* ws = (float*)d_ws;
    size_t o = 0;
    unsigned int* fubp = (unsigned int*)(ws + o); o += (size_t)Npad * 64;   // fused bf16; aliased by sort scratch early
    unsigned int* gx   = (unsigned int*)(ws + o); o += (size_t)Npad * 192;  // fs0|fs1|xb interleaved (768B rows)
    unsigned int* hgbp = (unsigned int*)(ws + o); o += (size_t)Npad * 64;   // bf16 hg*rsdi
    float* es0  = ws + o; o += (size_t)N * 4;
    float* es1  = ws + o; o += (size_t)N * 4;
    float* ed0  = ws + o; o += (size_t)N * 4;
    float* ed1  = ws + o; o += (size_t)N * 4;
    float* rsdo = ws + o; o += N;
    unsigned int* wtu = (unsigned int*)(ws + o); o += 32768;  // bf16 W^T x4 mats
    float* relfeat = ws + o; o += 256;
    unsigned short* wscb = (unsigned short*)(ws + o); o += 1024;  // bf16 score vectors [16][128] = 2048 ushorts = 1024 floats
    float* ces  = ws + o; o += 16;
    float* ced  = ws + o; o += 16;
    int* ip0  = (int*)(ws + o); o += N + 1;
    int* ip1  = (int*)(ws + o); o += N + 1;
    int* srcs0 = (int*)(ws + o); o += E;
    int* srcs1 = (int*)(ws + o); o += E;
    int* bucketTot  = (int*)(ws + o); o += 768;
    int* bucketBase = (int*)(ws + o); o += 771;
    int* cursor     = (int*)(ws + o); o += 768;
    // transient sort scratch aliased into fubp region (12 MB <= Npad*256B)
    unsigned int* pairs0 = (unsigned int*)fubp;                 // E uints
    unsigned int* pairs1 = pairs0 + (size_t)E;                  // E uints
    unsigned short* svals = (unsigned short*)(pairs1 + (size_t)E);  // RE ushorts

    const unsigned short* wts = (const unsigned short*)wtu;  // mat m at wts + m*16384

    hipMemsetAsync(bucketTot, 0, 768 * sizeof(int), stream);

    // K1: small | twt | count | x->bf16
    k_init<<<1 + 64 + NCB + CVB, 512, 0, stream>>>(rel_emb, W_relT, W_relprop, b_relprop, W_fuse,
                                                   W_src, b_src, W_node, b_node, W_g,
                                                   src, dst, x, E, RE,
                                                   relfeat, wscb, ces, ced, wtu, bucketTot, gx, N);
    // K2: bases
    k_bases<<<1, 256, 0, stream>>>(bucketTot, bucketBase, cursor, ip0, ip1, N, E);
    // K3: cscatter | mm + score GEMM
    k_scmm<<<NCB + 2 * MB, 256, 0, stream>>>(src, dst, E, RE, cursor, pairs0, pairs1, svals,
                                             gx, wts, wscb, b_src, ces, ced,
                                             es0, es1, ed0, ed1, MB, N);

    k_fine<<<dim3(NBUCK, 3), 512, 0, stream>>>(pairs0, pairs1, svals, bucketBase,
                                               ip0, ip1, srcs0, srcs1, rsdo, N);

    k_agg<<<(N + 7) / 8, 256, 0, stream>>>(ip0, srcs0, ip1, srcs1, gx,
                                           es0, es1, ed0, ed1, rsdo, relfeat, fubp, hgbp, N);

    k_fin<<<MB, 256, 0, stream>>>(hgbp, gx, wts + 3 * 16384, wts + 2 * 16384,
                                  b_g, b_node, fubp, resid_w, scale_w, out, N);
}

// Round 17
// 369.137 us; speedup vs baseline: 1.3699x; 1.0168x over previous
//
#include <hip/hip_runtime.h>
#include <cstddef>

#define NEG_SLOPE 0.2f

typedef __attribute__((ext_vector_type(8))) short bf16x8;
typedef __attribute__((ext_vector_type(4))) float f32x4;

__device__ __forceinline__ float leaky(float v) { return v >= 0.f ? v : NEG_SLOPE * v; }

__device__ __forceinline__ unsigned int bfpack(float a, float b) {
    unsigned int ua = __float_as_uint(a);
    ua += 0x7fffu + ((ua >> 16) & 1u);
    unsigned int ub = __float_as_uint(b);
    ub += 0x7fffu + ((ub >> 16) & 1u);
    return (ua >> 16) | (ub & 0xffff0000u);
}
__device__ __forceinline__ float bflo(unsigned int u) { return __uint_as_float(u << 16); }
__device__ __forceinline__ float bfhi(unsigned int u) { return __uint_as_float(u & 0xffff0000u); }
__device__ __forceinline__ float bfs(unsigned short u) { return __uint_as_float(((unsigned int)u) << 16); }

#define NCB 192   // coarse count/scatter blocks

// ===== K1: small-consts (b==0) | W^T transpose (b in [1,64]) | coarse count (b in [65,64+NCB]) | x->bf16 (rest) =====
__global__ __launch_bounds__(512) void k_init(const float* __restrict__ rel_emb, const float* __restrict__ W_relT,
                                              const float* __restrict__ W_relprop, const float* __restrict__ b_relprop,
                                              const float* __restrict__ W_fuse, const float* __restrict__ W_src,
                                              const float* __restrict__ b_src, const float* __restrict__ W_node,
                                              const float* __restrict__ b_node, const float* __restrict__ W_g,
                                              const int* __restrict__ src, const int* __restrict__ dst,
                                              const float* __restrict__ x,
                                              int E, int RE,
                                              float* __restrict__ relfeat, unsigned short* __restrict__ wscb,
                                              float* __restrict__ ces, float* __restrict__ ced,
                                              unsigned int* __restrict__ wt, int* __restrict__ bucketTot,
                                              int* __restrict__ blkHist,
                                              unsigned int* __restrict__ gx, int n) {
    __shared__ float av[512];
    __shared__ float rp[2][128];
    __shared__ int h0[256], h1[256], h2[256];
    int b = blockIdx.x;
    int t = threadIdx.x;
    if (b == 0) {
        {
            int r = t >> 8, m = t & 255;
            float acc = 0.f;
            const float* re = rel_emb + r * 64;
            const float* w = W_relT + (size_t)r * 16384 + m;
            #pragma unroll 8
            for (int k = 0; k < 64; ++k) acc += re[k] * w[(size_t)k * 256];
            av[t] = acc;
        }
        if (t < 256) {
            int r = t >> 7, m = t & 127;
            float acc = b_relprop[t];
            const float* re = rel_emb + r * 64;
            const float* w = W_relprop + (size_t)r * 8192 + m;
            #pragma unroll 8
            for (int k = 0; k < 64; ++k) acc += re[k] * w[(size_t)k * 128];
            rp[r][m] = acc;
        }
        __syncthreads();
        if (t < 256) {
            int r = t >> 7, h = (t >> 5) & 3, d = t & 31;
            float acc = 0.f;
            const float* w = W_fuse + ((size_t)(r * 4 + h) * 32) * 32 + d;
            #pragma unroll
            for (int k = 0; k < 32; ++k) acc += rp[r][h * 32 + k] * w[(size_t)k * 32];
            relfeat[t] = acc;
        }
        // score-projection vectors -> bf16 wscb[j][k], j = which*8 + r*4 + h
        for (int idx = t; idx < 2048; idx += 512) {
            int which = idx >> 10, rem = idx & 1023;
            int r = rem >> 9, h = (rem >> 7) & 3, c = rem & 127;
            const float* W = which ? W_node : (W_src + (size_t)r * 16384);
            const float* a = av + r * 256 + h * 64 + which * 32;
            float acc = 0.f;
            #pragma unroll
            for (int d = 0; d < 32; ++d) acc += W[(size_t)c * 128 + h * 32 + d] * a[d];
            int j = which * 8 + r * 4 + h;
            wscb[j * 128 + c] = (unsigned short)(bfpack(acc, 0.f) & 0xffffu);
        }
        if (t < 16) {
            int which = t >> 3, r = (t >> 2) & 1, h = t & 3;
            const float* bb = which ? b_node : (b_src + r * 128);
            const float* a = av + r * 256 + h * 64 + which * 32;
            float acc = 0.f;
            #pragma unroll
            for (int d = 0; d < 32; ++d) acc += bb[h * 32 + d] * a[d];
            (which ? ced : ces)[r * 4 + h] = acc;
        }
    } else if (b <= 64) {
        int idx = (b - 1) * 512 + t;   // 4*128*64 = 32768
        int mat = idx >> 13, rem = idx & 8191;
        int nrow = rem >> 6, kp = rem & 63;
        const float* W = mat < 2 ? W_src + (size_t)mat * 16384 : (mat == 2 ? W_node : W_g);
        wt[idx] = bfpack(W[(size_t)(2 * kp) * 128 + nrow], W[(size_t)(2 * kp + 1) * 128 + nrow]);
    } else if (b <= 64 + NCB) {
        if (t < 256) { h0[t] = 0; h1[t] = 0; h2[t] = 0; }
        __syncthreads();
        int cb = b - 65;
        int chunk = (RE + NCB - 1) / NCB;
        int lo = cb * chunk, hi = min(lo + chunk, RE);
        for (int i = lo + t; i < hi; i += 512) {
            int d = dst[i], s = src[i];
            atomicAdd((i < E ? h0 : h1) + (d >> 9), 1);
            atomicAdd(&h2[s >> 9], 1);
        }
        __syncthreads();
        if (t < 256) {
            int v0 = h0[t], v1 = h1[t], v2 = h2[t];
            blkHist[(cb * 3 + 0) * 256 + t] = v0;
            blkHist[(cb * 3 + 1) * 256 + t] = v1;
            blkHist[(cb * 3 + 2) * 256 + t] = v2;
            if (v0) atomicAdd(&bucketTot[t], v0);
            if (v1) atomicAdd(&bucketTot[256 + t], v1);
            if (v2) atomicAdd(&bucketTot[512 + t], v2);
        }
    } else {
        // x -> bf16 into gx xb section (128 rows per block)
        int nb0 = (b - 65 - NCB) * 128;
        for (int i = t; i < 128 * 32; i += 512) {
            int row = i >> 5, c4 = i & 31;
            int gr = nb0 + row;
            if (gr < n) {
                float4 v = *(const float4*)(x + (size_t)gr * 128 + c4 * 4);
                uint2 w;
                w.x = bfpack(v.x, v.y);
                w.y = bfpack(v.z, v.w);
                *(uint2*)(gx + (size_t)gr * 192 + 128 + c4 * 2) = w;
            }
        }
    }
}

// ===== K2: bucket-scan -> bases + cursors (1 block) =====
__global__ __launch_bounds__(256) void k_bases(const int* __restrict__ bucketTot,
                                               int* __restrict__ bucketBase, int* __restrict__ cursor,
                                               int* __restrict__ ip0, int* __restrict__ ip1,
                                               int N, int E) {
    __shared__ int sc[256];
    int t = threadIdx.x;
    for (int j = 0; j < 3; ++j) {
        int v = bucketTot[j * 256 + t];
        sc[t] = v;
        __syncthreads();
        for (int off = 1; off < 256; off <<= 1) {
            int tmp = (t >= off) ? sc[t - off] : 0;
            __syncthreads();
            sc[t] += tmp;
            __syncthreads();
        }
        int excl = sc[t] - v;
        bucketBase[j * 257 + t] = excl;
        if (t == 255) bucketBase[j * 257 + 256] = sc[255];
        cursor[j * 256 + t] = excl;
        __syncthreads();
    }
    if (t == 0) { ip0[N] = E; ip1[N] = E; }
}

// ===== K3: coarse scatter (b<NCB, reuses k_init histograms) | dual-relation MFMA GEMM + score GEMM (b>=NCB) =====
__global__ __launch_bounds__(256) void k_scmm(const int* __restrict__ src, const int* __restrict__ dst,
                                              int E, int RE, int* __restrict__ cursor,
                                              const int* __restrict__ blkHist,
                                              unsigned int* __restrict__ pairs0, unsigned int* __restrict__ pairs1,
                                              unsigned short* __restrict__ svals,
                                              unsigned int* __restrict__ gx,
                                              const unsigned short* __restrict__ wts,
                                              const unsigned short* __restrict__ wscb,
                                              const float* __restrict__ b_src,
                                              const float* __restrict__ ces, const float* __restrict__ ced,
                                              float* __restrict__ es0, float* __restrict__ es1,
                                              float* __restrict__ ed0, float* __restrict__ ed1,
                                              int MB, int n) {
    if (blockIdx.x < NCB) {
        __shared__ int c0[256], c1[256], c2[256];
        int t = threadIdx.x;
        int cb = blockIdx.x;
        int h0v = blkHist[(cb * 3 + 0) * 256 + t];
        int h1v = blkHist[(cb * 3 + 1) * 256 + t];
        int h2v = blkHist[(cb * 3 + 2) * 256 + t];
        if (h0v) c0[t] = atomicAdd(&cursor[t], h0v);
        if (h1v) c1[t] = atomicAdd(&cursor[256 + t], h1v);
        if (h2v) c2[t] = atomicAdd(&cursor[512 + t], h2v);
        __syncthreads();
        int chunk = (RE + NCB - 1) / NCB;
        int lo = cb * chunk, hi = min(lo + chunk, RE);
        for (int i = lo + t; i < hi; i += 256) {
            int d = dst[i], s = src[i];
            unsigned int packed = ((unsigned)(d & 511) << 23) | (unsigned)s;
            if (i < E) {
                int pos = atomicAdd(&c0[d >> 9], 1);
                pairs0[pos] = packed;
            } else {
                int pos = atomicAdd(&c1[d >> 9], 1);
                pairs1[pos] = packed;
            }
            int pos2 = atomicAdd(&c2[s >> 9], 1);
            svals[pos2] = (unsigned short)(s & 511);
        }
        return;
    }
    int q = blockIdx.x - NCB;
    int rel = q / MB, mb = q % MB;
    const unsigned short* wT = wts + (size_t)rel * 16384;
    const float* bias = b_src + rel * 128;
    int wid = threadIdx.x >> 6, lane = threadIdx.x & 63;
    int l15 = lane & 15, g = lane >> 4;
    int m0 = mb * 128 + wid * 32;
    const unsigned short* Au = (const unsigned short*)gx;   // xb at row*384 + 256
    f32x4 acc[2][8];
    f32x4 asc[2];
    #pragma unroll
    for (int mt = 0; mt < 2; ++mt) {
        #pragma unroll
        for (int nt = 0; nt < 8; ++nt)
            #pragma unroll
            for (int r = 0; r < 4; ++r) acc[mt][nt][r] = 0.f;
        #pragma unroll
        for (int r = 0; r < 4; ++r) asc[mt][r] = 0.f;
    }
    #pragma unroll
    for (int t = 0; t < 4; ++t) {
        bf16x8 a0 = *(const bf16x8*)(Au + (size_t)(m0 + l15) * 384 + 256 + t * 32 + g * 8);
        bf16x8 a1 = *(const bf16x8*)(Au + (size_t)(m0 + 16 + l15) * 384 + 256 + t * 32 + g * 8);
        #pragma unroll
        for (int nt = 0; nt < 8; ++nt) {
            bf16x8 b = *(const bf16x8*)(wT + (size_t)(nt * 16 + l15) * 128 + t * 32 + g * 8);
            acc[0][nt] = __builtin_amdgcn_mfma_f32_16x16x32_bf16(a0, b, acc[0][nt], 0, 0, 0);
            acc[1][nt] = __builtin_amdgcn_mfma_f32_16x16x32_bf16(a1, b, acc[1][nt], 0, 0, 0);
        }
        if (rel == 0) {
            bf16x8 bs = *(const bf16x8*)(wscb + l15 * 128 + t * 32 + g * 8);
            asc[0] = __builtin_amdgcn_mfma_f32_16x16x32_bf16(a0, bs, asc[0], 0, 0, 0);
            asc[1] = __builtin_amdgcn_mfma_f32_16x16x32_bf16(a1, bs, asc[1], 0, 0, 0);
        }
    }
    #pragma unroll
    for (int mt = 0; mt < 2; ++mt)
        #pragma unroll
        for (int nt = 0; nt < 8; ++nt) {
            int col = nt * 16 + l15;
            float bv = bias[col];
            #pragma unroll
            for (int r = 0; r < 4; ++r) {
                int row = m0 + mt * 16 + g * 4 + r;
                float v = acc[mt][nt][r] + bv;
                float vp = __shfl_xor(v, 1);
                if (!(l15 & 1) && row < n)
                    gx[(size_t)row * 192 + rel * 64 + (col >> 1)] = bfpack(v, vp);
            }
        }
    if (rel == 0) {
        int which = l15 >> 3, rr = (l15 >> 2) & 1, h = l15 & 3;
        float bsc = (which ? ced : ces)[l15 & 7];
        float* outp = which ? (rr ? ed1 : ed0) : (rr ? es1 : es0);
        #pragma unroll
        for (int mt = 0; mt < 2; ++mt)
            #pragma unroll
            for (int r = 0; r < 4; ++r) {
                int row = m0 + mt * 16 + g * 4 + r;
                if (row < n) outp[(size_t)row * 4 + h] = asc[mt][r] + bsc;
            }
    }
}

// ---------- stage 4 (3 jobs): per-bucket fine sort (r=0,1) + src out-degree -> rsdo (r=2) ----------
__global__ __launch_bounds__(512) void k_fine(const unsigned int* __restrict__ pairs0,
                                              const unsigned int* __restrict__ pairs1,
                                              const unsigned short* __restrict__ svals,
                                              const int* __restrict__ bucketBase,
                                              int* __restrict__ ip0, int* __restrict__ ip1,
                                              int* __restrict__ srcs0, int* __restrict__ srcs1,
                                              float* __restrict__ rsdo, int N) {
    int r = blockIdx.y;
    int b = blockIdx.x;
    __shared__ int hist[512];
    int t = threadIdx.x;
    hist[t] = 0;
    __syncthreads();
    if (r == 2) {   // src out-degree histogram
        int ebase = bucketBase[2 * 257 + b], eend = bucketBase[2 * 257 + b + 1];
        for (int k = ebase + t; k < eend; k += 512)
            atomicAdd(&hist[svals[k]], 1);
        __syncthreads();
        int node = (b << 9) + t;
        if (node < N) rsdo[node] = rsqrtf(fmaxf((float)hist[t], 1.f));
        return;
    }
    const unsigned int* pairs = r ? pairs1 : pairs0;
    int* ip = r ? ip1 : ip0;
    int* srcs = r ? srcs1 : srcs0;
    int ebase = bucketBase[r * 257 + b], eend = bucketBase[r * 257 + b + 1];
    for (int k = ebase + t; k < eend; k += 512)
        atomicAdd(&hist[pairs[k] >> 23], 1);
    __syncthreads();
    int v = hist[t];
    for (int off = 1; off < 512; off <<= 1) {
        int tmp = (t >= off) ? hist[t - off] : 0;
        __syncthreads();
        hist[t] += tmp;
        __syncthreads();
    }
    int excl = hist[t] - v;
    int node = (b << 9) + t;
    if (node < N) ip[node] = ebase + excl;
    __syncthreads();
    hist[t] = ebase + excl;  // reuse as scatter cursor
    __syncthreads();
    for (int k = ebase + t; k < eend; k += 512) {
        unsigned int p = pairs[k];
        int pos = atomicAdd(&hist[p >> 23], 1);
        srcs[pos] = (int)(p & 0x7FFFFFu);
    }
}

// ---------- CSR gather-aggregate: TWO nodes per wave (32 lanes, 4 ch/lane), uint2 gathers ----------
__global__ __launch_bounds__(256) void k_agg(const int* __restrict__ ip0, const int* __restrict__ srcs0,
                                             const int* __restrict__ ip1, const int* __restrict__ srcs1,
                                             const unsigned int* __restrict__ gx,
                                             const float* __restrict__ es0, const float* __restrict__ es1,
                                             const float* __restrict__ ed0, const float* __restrict__ ed1,
                                             const float* __restrict__ rsdo,
                                             const float* __restrict__ relfeat,
                                             unsigned int* __restrict__ fubp, unsigned int* __restrict__ hgbp, int n) {
    int node = blockIdx.x * 8 + (threadIdx.x >> 5);   // one node per 32-lane half-wave
    if (node >= n) return;
    int l = threadIdx.x & 31;                          // channels 4l .. 4l+3
    int h = l >> 3;
    float ed0v = ed0[(size_t)node * 4 + h];
    float ed1v = ed1[(size_t)node * 4 + h];
    float aU0[4] = {0.f, 0.f, 0.f, 0.f};
    float aU1[4] = {0.f, 0.f, 0.f, 0.f};
    float aH[4]  = {0.f, 0.f, 0.f, 0.f};
    float s0 = 0.f, s1 = 0.f;
    int b0 = ip0[node], e0 = ip0[node + 1];
    #pragma unroll 4
    for (int k = b0; k < e0; ++k) {
        int s = srcs0[k];
        float ex = __expf(leaky(es0[(size_t)s * 4 + h] + ed0v));
        float rs = rsdo[s];
        size_t base = (size_t)s * 192;
        uint2 fv = *(const uint2*)(gx + base + 2 * l);
        uint2 xv = *(const uint2*)(gx + base + 128 + 2 * l);
        aU0[0] += ex * bflo(fv.x); aU0[1] += ex * bfhi(fv.x);
        aU0[2] += ex * bflo(fv.y); aU0[3] += ex * bfhi(fv.y);
        aH[0] += rs * bflo(xv.x); aH[1] += rs * bfhi(xv.x);
        aH[2] += rs * bflo(xv.y); aH[3] += rs * bfhi(xv.y);
        s0 += ex;
    }
    int b1 = ip1[node], e1 = ip1[node + 1];
    #pragma unroll 4
    for (int k = b1; k < e1; ++k) {
        int s = srcs1[k];
        float ex = __expf(leaky(es1[(size_t)s * 4 + h] + ed1v));
        float rs = rsdo[s];
        size_t base = (size_t)s * 192;
        uint2 fv = *(const uint2*)(gx + base + 64 + 2 * l);
        uint2 xv = *(const uint2*)(gx + base + 128 + 2 * l);
        aU1[0] += ex * bflo(fv.x); aU1[1] += ex * bfhi(fv.x);
        aU1[2] += ex * bflo(fv.y); aU1[3] += ex * bfhi(fv.y);
        aH[0] += rs * bflo(xv.x); aH[1] += rs * bfhi(xv.x);
        aH[2] += rs * bflo(xv.y); aH[3] += rs * bfhi(xv.y);
        s1 += ex;
    }
    float i0 = 1.f / (s0 + 1e-9f), i1 = 1.f / (s1 + 1e-9f);
    float f0[4], f1[4];
    #pragma unroll
    for (int c = 0; c < 4; ++c) {
        f0[c] = fmaxf(aU0[c] * i0, 0.f);
        f1[c] = fmaxf(aU1[c] * i1, 0.f);
    }
    float sc0 = 0.f, sc1 = 0.f;
    #pragma unroll
    for (int c = 0; c < 4; ++c) {
        sc0 += f0[c] * relfeat[4 * l + c];
        sc1 += f1[c] * relfeat[128 + 4 * l + c];
    }
    #pragma unroll
    for (int m = 1; m < 8; m <<= 1) {     // reduce over the 8-lane head group
        sc0 += __shfl_xor(sc0, m, 64);
        sc1 += __shfl_xor(sc1, m, 64);
    }
    sc0 = leaky(sc0); sc1 = leaky(sc1);
    float mx = fmaxf(sc0, sc1);
    float p0 = __expf(sc0 - mx), p1 = __expf(sc1 - mx);
    float inv = 1.f / (p0 + p1);
    p0 *= inv; p1 *= inv;
    float rv = rsqrtf(fmaxf((float)((e0 - b0) + (e1 - b1)), 1.f));
    uint2 fo, ho;
    fo.x = bfpack(p0 * f0[0] + p1 * f1[0], p0 * f0[1] + p1 * f1[1]);
    fo.y = bfpack(p0 * f0[2] + p1 * f1[2], p0 * f0[3] + p1 * f1[3]);
    ho.x = bfpack(aH[0] * rv, aH[1] * rv);
    ho.y = bfpack(aH[2] * rv, aH[3] * rv);
    *(uint2*)(fubp + (size_t)node * 64 + 2 * l) = fo;
    *(uint2*)(hgbp + (size_t)node * 64 + 2 * l) = ho;
}

// ---------- final: two MFMA GEMMs (hgb @ Wg, xb @ Wn) + fusion epilogue ----------
__global__ __launch_bounds__(256) void k_fin(const unsigned int* __restrict__ hgbp,
                                             const unsigned int* __restrict__ gx,
                                             const unsigned short* __restrict__ wtg,
                                             const unsigned short* __restrict__ wtn,
                                             const float* __restrict__ bg, const float* __restrict__ bn,
                                             const unsigned int* __restrict__ fubp,
                                             const float* __restrict__ residual_w, const float* __restrict__ scale_w,
                                             float* __restrict__ out, int n) {
    int wid = threadIdx.x >> 6, lane = threadIdx.x & 63;
    int l15 = lane & 15, g = lane >> 4;
    int m0 = blockIdx.x * 128 + wid * 32;
    const unsigned short* Hu = (const unsigned short*)hgbp;
    const unsigned short* Xu = (const unsigned short*)gx;   // xb at row*384 + 256
    const unsigned short* Fu = (const unsigned short*)fubp;
    f32x4 accn[2][8], accg[2][8];
    #pragma unroll
    for (int mt = 0; mt < 2; ++mt)
        #pragma unroll
        for (int nt = 0; nt < 8; ++nt)
            #pragma unroll
            for (int r = 0; r < 4; ++r) { accn[mt][nt][r] = 0.f; accg[mt][nt][r] = 0.f; }
    #pragma unroll
    for (int t = 0; t < 4; ++t) {
        bf16x8 a0 = *(const bf16x8*)(Xu + (size_t)(m0 + l15) * 384 + 256 + t * 32 + g * 8);
        bf16x8 a1 = *(const bf16x8*)(Xu + (size_t)(m0 + 16 + l15) * 384 + 256 + t * 32 + g * 8);
        #pragma unroll
        for (int nt = 0; nt < 8; ++nt) {
            bf16x8 b = *(const bf16x8*)(wtn + (size_t)(nt * 16 + l15) * 128 + t * 32 + g * 8);
            accn[0][nt] = __builtin_amdgcn_mfma_f32_16x16x32_bf16(a0, b, accn[0][nt], 0, 0, 0);
            accn[1][nt] = __builtin_amdgcn_mfma_f32_16x16x32_bf16(a1, b, accn[1][nt], 0, 0, 0);
        }
    }
    #pragma unroll
    for (int t = 0; t < 4; ++t) {
        bf16x8 a0 = *(const bf16x8*)(Hu + (size_t)(m0 + l15) * 128 + t * 32 + g * 8);
        bf16x8 a1 = *(const bf16x8*)(Hu + (size_t)(m0 + 16 + l15) * 128 + t * 32 + g * 8);
        #pragma unroll
        for (int nt = 0; nt < 8; ++nt) {
            bf16x8 b = *(const bf16x8*)(wtg + (size_t)(nt * 16 + l15) * 128 + t * 32 + g * 8);
            accg[0][nt] = __builtin_amdgcn_mfma_f32_16x16x32_bf16(a0, b, accg[0][nt], 0, 0, 0);
            accg[1][nt] = __builtin_amdgcn_mfma_f32_16x16x32_bf16(a1, b, accg[1][nt], 0, 0, 0);
        }
    }
    float beta = 1.f / (1.f + __expf(-residual_w[0]));
    float av = 1.f / (1.f + __expf(-scale_w[0]));
    #pragma unroll
    for (int mt = 0; mt < 2; ++mt)
        #pragma unroll
        for (int nt = 0; nt < 8; ++nt) {
            int col = nt * 16 + l15;
            float bnv = bn[col], bgv = bg[col];
            #pragma unroll
            for (int r = 0; r < 4; ++r) {
                int row = m0 + mt * 16 + g * 4 + r;
                if (row < n) {
                    float fu = bfs(Fu[(size_t)row * 128 + col]);
                    float fd = accn[mt][nt][r] + bnv;
                    float f = beta * fu + (1.f - beta) * fd;
                    float nl = fmaxf(accg[mt][nt][r] + bgv, 0.f);
                    out[(size_t)row * 128 + col] = av * f + (1.f - av) * nl;
                }
            }
        }
}

extern "C" void kernel_launch(void* const* d_in, const int* in_sizes, int n_in,
                              void* d_out, int out_size, void* d_ws, size_t ws_size,
                              hipStream_t stream) {
    const float* x         = (const float*)d_in[0];
    const int*   src       = (const int*)d_in[1];
    const int*   dst       = (const int*)d_in[2];
    const float* rel_emb   = (const float*)d_in[3];
    const float* W_node    = (const float*)d_in[4];
    const float* b_node    = (const float*)d_in[5];
    const float* W_src     = (const float*)d_in[6];
    const float* b_src     = (const float*)d_in[7];
    const float* W_relT    = (const float*)d_in[8];
    const float* W_relprop = (const float*)d_in[9];
    const float* b_relprop = (const float*)d_in[10];
    const float* W_fuse    = (const float*)d_in[11];
    const float* resid_w   = (const float*)d_in[12];
    const float* scale_w   = (const float*)d_in[13];
    const float* W_g       = (const float*)d_in[14];
    const float* b_g       = (const float*)d_in[15];
    float* out = (float*)d_out;

    const int N = in_sizes[0] / 128;
    const int RE = in_sizes[1];
    const int E = RE / 2;
    const int Npad = (N + 127) & ~127;
    const int NBUCK = (N + 511) >> 9;
    const int MB = Npad / 128;
    const int CVB = (N + 127) / 128;

    // workspace (~145 MB at N=1e5, E=1e6)
    float* ws = (float*)d_ws;
    size_t o = 0;
    unsigned int* fubp = (unsigned int*)(ws + o); o += (size_t)Npad * 64;   // fused bf16; aliased by sort scratch early
    unsigned int* gx   = (unsigned int*)(ws + o); o += (size_t)Npad * 192;  // fs0|fs1|xb interleaved (768B rows)
    unsigned int* hgbp = (unsigned int*)(ws + o); o += (size_t)Npad * 64;   // bf16 hg*rsdi
    float* es0  = ws + o; o += (size_t)N * 4;
    float* es1  = ws + o; o += (size_t)N * 4;
    float* ed0  = ws + o; o += (size_t)N * 4;
    float* ed1  = ws + o; o += (size_t)N * 4;
    float* rsdo = ws + o; o += N;
    unsigned int* wtu = (unsigned int*)(ws + o); o += 32768;  // bf16 W^T x4 mats
    float* relfeat = ws + o; o += 256;
    unsigned short* wscb = (unsigned short*)(ws + o); o += 1024;  // bf16 score vectors [16][128]
    float* ces  = ws + o; o += 16;
    float* ced  = ws + o; o += 16;
    int* ip0  = (int*)(ws + o); o += N + 1;
    int* ip1  = (int*)(ws + o); o += N + 1;
    int* srcs0 = (int*)(ws + o); o += E;
    int* srcs1 = (int*)(ws + o); o += E;
    int* bucketTot  = (int*)(ws + o); o += 768;
    int* bucketBase = (int*)(ws + o); o += 771;
    int* cursor     = (int*)(ws + o); o += 768;
    int* blkHist    = (int*)(ws + o); o += (size_t)NCB * 3 * 256;
    // transient sort scratch aliased into fubp region (12 MB <= Npad*256B)
    unsigned int* pairs0 = (unsigned int*)fubp;                 // E uints
    unsigned int* pairs1 = pairs0 + (size_t)E;                  // E uints
    unsigned short* svals = (unsigned short*)(pairs1 + (size_t)E);  // RE ushorts

    const unsigned short* wts = (const unsigned short*)wtu;  // mat m at wts + m*16384

    hipMemsetAsync(bucketTot, 0, 768 * sizeof(int), stream);

    // K1: small | twt | count | x->bf16
    k_init<<<1 + 64 + NCB + CVB, 512, 0, stream>>>(rel_emb, W_relT, W_relprop, b_relprop, W_fuse,
                                                   W_src, b_src, W_node, b_node, W_g,
                                                   src, dst, x, E, RE,
                                                   relfeat, wscb, ces, ced, wtu, bucketTot, blkHist, gx, N);
    // K2: bases
    k_bases<<<1, 256, 0, stream>>>(bucketTot, bucketBase, cursor, ip0, ip1, N, E);
    // K3: cscatter | mm + score GEMM
    k_scmm<<<NCB + 2 * MB, 256, 0, stream>>>(src, dst, E, RE, cursor, blkHist, pairs0, pairs1, svals,
                                             gx, wts, wscb, b_src, ces, ced,
                                             es0, es1, ed0, ed1, MB, N);

    k_fine<<<dim3(NBUCK, 3), 512, 0, stream>>>(pairs0, pairs1, svals, bucketBase,
                                               ip0, ip1, srcs0, srcs1, rsdo, N);

    k_agg<<<(N + 7) / 8, 256, 0, stream>>>(ip0, srcs0, ip1, srcs1, gx,
                                           es0, es1, ed0, ed1, rsdo, relfeat, fubp, hgbp, N);

    k_fin<<<MB, 256, 0, stream>>>(hgbp, gx, wts + 3 * 16384, wts + 2 * 16384,
                                  b_g, b_node, fubp, resid_w, scale_w, out, N);
}